// Round 5
// baseline (8249.447 us; speedup 1.0000x reference)
//
#include <hip/hip_runtime.h>
#include <hip/hip_bf16.h>
#include <cstdint>
#include <cstddef>

// Autoformer forward, MI355X. Round 5: r4 (passing, split-bf16 MFMA) plus:
//   - gather: per-(b,half) LDS-staged V (was 118k-block L2 thrash, 3.4ms total)
//   - top-k fused into corr kernel (drops 10 launches + corr buffer)
//   - GEMM nt-fast tile order (X-stripe L2 reuse across N-tiles)
#define B_   1024
#define LE   96
#define LD   116
#define DM   256
#define DFF  1024

typedef __attribute__((ext_vector_type(8))) short bf16x8;
typedef __attribute__((ext_vector_type(4))) float f32x4;

static __device__ __forceinline__ unsigned short f2b(float f) {
  __hip_bfloat16 h = __float2bfloat16(f);
  return *reinterpret_cast<unsigned short*>(&h);
}
static __device__ __forceinline__ float asf(unsigned int u) { return __uint_as_float(u); }

// split 8 f32 -> 8 bf16 hi + 8 bf16 lo (x = hi + lo, residual ~2^-18 relative)
static __device__ __forceinline__ void split8(float4 a, float4 b, uint4& h4, uint4& l4) {
  float f[8] = {a.x, a.y, a.z, a.w, b.x, b.y, b.z, b.w};
  unsigned int hp[4], lp[4];
#pragma unroll
  for (int j = 0; j < 4; ++j) {
    unsigned short h0 = f2b(f[2 * j]);
    unsigned short h1 = f2b(f[2 * j + 1]);
    float r0 = f[2 * j]     - asf((unsigned int)h0 << 16);
    float r1 = f[2 * j + 1] - asf((unsigned int)h1 << 16);
    hp[j] = (unsigned int)h0 | ((unsigned int)h1 << 16);
    lp[j] = (unsigned int)f2b(r0) | ((unsigned int)f2b(r1) << 16);
  }
  h4 = make_uint4(hp[0], hp[1], hp[2], hp[3]);
  l4 = make_uint4(lp[0], lp[1], lp[2], lp[3]);
}

typedef const __attribute__((address_space(1))) void* gas_ptr;
typedef __attribute__((address_space(3))) void* las_ptr;
static __device__ __forceinline__ void gload16(const void* g, void* l) {
  __builtin_amdgcn_global_load_lds((gas_ptr)g, (las_ptr)l, 16, 0, 0);
}

// ---------------- workspace (static; ws_size-independent) ----------------
#define NE_ ((size_t)B_ * LE * DM)
#define ND_ ((size_t)B_ * LD * DM)
#define NS_ ((size_t)B_ * LD * 5)
#define NW_ ((size_t)B_ * 16)
#define WBF_ 3670016

static constexpr size_t o_enc   = 0;
static constexpr size_t o_dec   = o_enc   + NE_ * 4;
static constexpr size_t o_q     = o_dec   + ND_ * 4;
static constexpr size_t o_kbuf  = o_q     + ND_ * 4;
static constexpr size_t o_spad  = o_kbuf  + ND_ * 4;
static constexpr size_t o_trend = o_spad  + NS_ * 4;
static constexpr size_t o_wtop  = o_trend + NS_ * 4;
static constexpr size_t o_dtop  = o_wtop  + NW_ * 4;
static constexpr size_t o_whi   = o_dtop  + NW_ * 4;
static constexpr size_t o_wlo   = o_whi   + (size_t)WBF_ * 2;
static constexpr size_t WS_TOTAL = o_wlo  + (size_t)WBF_ * 2;

__device__ __align__(256) unsigned char g_ws[WS_TOTAL];

static constexpr size_t wq_e = 0, wk_e = 131072, wv_e = 262144, wo_e = 393216;
static constexpr size_t w1_e = 524288, w2_e = 1048576;
static constexpr size_t swq_e = 1572864, swk_e = 1703936, swv_e = 1835008, swo_e = 1966080;
static constexpr size_t cwq_e = 2097152, cwk_e = 2228224, cwv_e = 2359296, cwo_e = 2490368;
static constexpr size_t dw1_e = 2621440, dw2_e = 3145728;

// ---------------- weight split cast ----------------
__global__ __launch_bounds__(256)
void k_cast_split(const float* __restrict__ in, unsigned short* __restrict__ hi,
                  unsigned short* __restrict__ lo, int n) {
  int i = (blockIdx.x * 256 + threadIdx.x) * 4;
  if (i < n) {
    float4 v = *(const float4*)(in + i);
    unsigned int hp[2], lp[2];
    float f[4] = {v.x, v.y, v.z, v.w};
#pragma unroll
    for (int j = 0; j < 2; ++j) {
      unsigned short h0 = f2b(f[2 * j]);
      unsigned short h1 = f2b(f[2 * j + 1]);
      float r0 = f[2 * j]     - asf((unsigned int)h0 << 16);
      float r1 = f[2 * j + 1] - asf((unsigned int)h1 << 16);
      hp[j] = (unsigned int)h0 | ((unsigned int)h1 << 16);
      lp[j] = (unsigned int)f2b(r0) | ((unsigned int)f2b(r1) << 16);
    }
    *(uint2*)(hi + i) = make_uint2(hp[0], hp[1]);
    *(uint2*)(lo + i) = make_uint2(lp[0], lp[1]);
  }
}

// ---------------- preprocess ----------------
__global__ __launch_bounds__(128)
void k_pre(const float* __restrict__ x, float* __restrict__ spad, float* __restrict__ trend) {
  int b = blockIdx.x;
  __shared__ float xs[LE * 5];
  __shared__ float mx[5];
  const float* xb = x + (size_t)b * LE * 5;
  for (int i = threadIdx.x; i < LE * 5; i += 128) xs[i] = xb[i];
  __syncthreads();
  if (threadIdx.x < 5) {
    float s = 0.f;
    for (int t = 0; t < LE; ++t) s += xs[t * 5 + threadIdx.x];
    mx[threadIdx.x] = s * (1.f / 96.f);
  }
  __syncthreads();
  float* spb = spad + (size_t)b * LD * 5;
  float* trb = trend + (size_t)b * LD * 5;
  for (int i = threadIdx.x; i < LE * 5; i += 128) {
    int t = i / 5, c = i % 5;
    float s = 0.f;
    for (int d = -12; d <= 12; ++d) {
      int tt = t + d; tt = tt < 0 ? 0 : (tt > LE - 1 ? LE - 1 : tt);
      s += xs[tt * 5 + c];
    }
    float m = s * (1.f / 25.f);
    trb[t * 5 + c] = m;
    spb[(t + 20) * 5 + c] = xs[i] - m;
  }
  for (int i = threadIdx.x; i < 20 * 5; i += 128) {
    int t = i / 5, c = i % 5;
    spb[t * 5 + c] = 0.f;
    trb[(LE + t) * 5 + c] = mx[c];
  }
}

// ---------------- circular 3-tap conv ----------------
__global__ __launch_bounds__(256)
void k_conv3(const float* __restrict__ xin, const float* __restrict__ W,
             float* __restrict__ out, int L) {
  int b = blockIdx.x, o = threadIdx.x;
  __shared__ float xs[LD * 5];
  const float* xb = xin + (size_t)b * L * 5;
  for (int i = o; i < L * 5; i += 256) xs[i] = xb[i];
  __syncthreads();
  float w[15];
#pragma unroll
  for (int j = 0; j < 15; ++j) w[j] = W[o * 15 + j];
  float* ob = out + (size_t)b * L * DM;
  for (int l = 0; l < L; ++l) {
    int lm = (l == 0) ? L - 1 : l - 1;
    int lp = (l == L - 1) ? 0 : l + 1;
    float acc = 0.f;
#pragma unroll
    for (int c = 0; c < 5; ++c)
      acc += xs[lm * 5 + c] * w[c * 3] + xs[l * 5 + c] * w[c * 3 + 1] + xs[lp * 5 + c] * w[c * 3 + 2];
    ob[(size_t)l * DM + o] = acc;
  }
}

// ---------------- split-bf16 MFMA GEMM (f32-accurate) ----------------
// 128x128 tile, BK=32, 4 waves (2x2 of 64x64). nt-fast tile order for X L2 reuse.
template <bool RELU>
__global__ __launch_bounds__(256)
void k_gemm_split(const float* __restrict__ X,
                  const unsigned short* __restrict__ Whi, const unsigned short* __restrict__ Wlo,
                  const float* __restrict__ bias, float* __restrict__ C,
                  int M, int N, int K) {
  __shared__ __align__(16) unsigned short Xh[4096], Xl[4096], Wh[4096], Wl[4096];
  const int nwg = gridDim.x, bid = blockIdx.x;
  const int wg = (bid & 7) * (nwg >> 3) + (bid >> 3);   // XCD swizzle (nwg%8==0 here)
  const int NT = N >> 7;
  const int mt = wg / NT, nt = wg % NT;                 // nt-fast: X stripe reused on-XCD
  const int m0 = mt << 7, n0 = nt << 7;
  const int tid = threadIdx.x, lane = tid & 63, wv = tid >> 6;
  const int wm = (wv >> 1) << 6, wn = (wv & 1) << 6;

  f32x4 acc[4][4];
#pragma unroll
  for (int i = 0; i < 4; ++i)
#pragma unroll
    for (int j = 0; j < 4; ++j) acc[i][j] = (f32x4){0.f, 0.f, 0.f, 0.f};

  const int r0 = tid >> 2,        ls0 = (tid & 3) ^ ((r0 >> 1) & 3);
  const int r1 = 64 + (tid >> 2), ls1 = (tid & 3) ^ ((r1 >> 1) & 3);
  const unsigned short* wh0 = Whi + (size_t)(n0 + r0) * K + (ls0 << 3);
  const unsigned short* wh1 = Whi + (size_t)(n0 + r1) * K + (ls1 << 3);
  const unsigned short* wl0 = Wlo + (size_t)(n0 + r0) * K + (ls0 << 3);
  const unsigned short* wl1 = Wlo + (size_t)(n0 + r1) * K + (ls1 << 3);
  unsigned short* lwh0 = Wh + ((tid & ~63) << 3);
  unsigned short* lwh1 = Wh + 2048 + ((tid & ~63) << 3);
  unsigned short* lwl0 = Wl + ((tid & ~63) << 3);
  unsigned short* lwl1 = Wl + 2048 + ((tid & ~63) << 3);

  const int xrow0 = tid >> 2, xpart = tid & 3;
  const int xrow1 = 64 + xrow0;
  const float* xp0 = X + (size_t)(m0 + xrow0) * K + (xpart << 3);
  const float* xp1 = X + (size_t)(m0 + xrow1) * K + (xpart << 3);
  const int xph0 = xpart ^ ((xrow0 >> 1) & 3);
  const int xph1 = xpart ^ ((xrow1 >> 1) & 3);
  unsigned short* xh0d = Xh + xrow0 * 32 + (xph0 << 3);
  unsigned short* xl0d = Xl + xrow0 * 32 + (xph0 << 3);
  unsigned short* xh1d = Xh + xrow1 * 32 + (xph1 << 3);
  unsigned short* xl1d = Xl + xrow1 * 32 + (xph1 << 3);

  for (int k0 = 0; k0 < K; k0 += 32) {
    gload16(wh0 + k0, lwh0);
    gload16(wh1 + k0, lwh1);
    gload16(wl0 + k0, lwl0);
    gload16(wl1 + k0, lwl1);
    {
      float4 a0 = *(const float4*)(xp0 + k0);
      float4 b0 = *(const float4*)(xp0 + k0 + 4);
      float4 a1 = *(const float4*)(xp1 + k0);
      float4 b1 = *(const float4*)(xp1 + k0 + 4);
      uint4 h, l;
      split8(a0, b0, h, l);
      *(uint4*)xh0d = h; *(uint4*)xl0d = l;
      split8(a1, b1, h, l);
      *(uint4*)xh1d = h; *(uint4*)xl1d = l;
    }
    __syncthreads();
    bf16x8 ah[4], al[4], bh[4], bl[4];
#pragma unroll
    for (int i = 0; i < 4; ++i) {
      int ra = wm + i * 16 + (lane & 15);
      int sa = (lane >> 4) ^ ((ra >> 1) & 3);
      ah[i] = *(const bf16x8*)(Xh + ra * 32 + (sa << 3));
      al[i] = *(const bf16x8*)(Xl + ra * 32 + (sa << 3));
      int rb = wn + i * 16 + (lane & 15);
      int sb = (lane >> 4) ^ ((rb >> 1) & 3);
      bh[i] = *(const bf16x8*)(Wh + rb * 32 + (sb << 3));
      bl[i] = *(const bf16x8*)(Wl + rb * 32 + (sb << 3));
    }
#pragma unroll
    for (int i = 0; i < 4; ++i)
#pragma unroll
      for (int j = 0; j < 4; ++j) {
        acc[i][j] = __builtin_amdgcn_mfma_f32_16x16x32_bf16(ah[i], bh[j], acc[i][j], 0, 0, 0);
        acc[i][j] = __builtin_amdgcn_mfma_f32_16x16x32_bf16(al[i], bh[j], acc[i][j], 0, 0, 0);
        acc[i][j] = __builtin_amdgcn_mfma_f32_16x16x32_bf16(ah[i], bl[j], acc[i][j], 0, 0, 0);
      }
    __syncthreads();
  }

  const int col_base = n0 + wn + (lane & 15);
  const int row_base = m0 + wm + ((lane >> 4) << 2);
#pragma unroll
  for (int j = 0; j < 4; ++j) {
    int col = col_base + j * 16;
    float bv = bias ? bias[col] : 0.f;
#pragma unroll
    for (int i = 0; i < 4; ++i) {
      int rb2 = row_base + i * 16;
#pragma unroll
      for (int q = 0; q < 4; ++q) {
        float o = acc[i][j][q] + bv;
        if (RELU) o = fmaxf(o, 0.f);
        C[(size_t)(rb2 + q) * N + col] = o;
      }
    }
  }
}

// ---------------- corr (split-bf16 MFMA Gram) + fused top-k/softmax ----------------
// corr[b,tau] = (1/256) sum_t <Q[b,t,:], K[b,(t-tau)%L,:]>, K rows >= S zero.
__global__ __launch_bounds__(256)
void k_corr_split(const float* __restrict__ Q, const float* __restrict__ Kp,
                  float* __restrict__ wout, int* __restrict__ dout,
                  int L, int S, int TK) {
  __shared__ __align__(16) unsigned char smem[65536];
  unsigned short* qh = (unsigned short*)smem;   // [128][64]
  unsigned short* ql = qh + 8192;
  unsigned short* kh = ql + 8192;
  unsigned short* kl = kh + 8192;
  float* G = (float*)smem;                      // [128][128] overlays after K-loop
  int b = blockIdx.x, tid = threadIdx.x, lane = tid & 63, wv = tid >> 6;
  int wm = (wv >> 1) << 6, wn = (wv & 1) << 6;
  const float* Qb = Q + (size_t)b * L * DM;
  const float* Kb = Kp + (size_t)b * S * DM;
  f32x4 acc[4][4];
#pragma unroll
  for (int i = 0; i < 4; ++i)
#pragma unroll
    for (int j = 0; j < 4; ++j) acc[i][j] = (f32x4){0.f, 0.f, 0.f, 0.f};

  for (int c0 = 0; c0 < DM; c0 += 64) {
#pragma unroll
    for (int u = 0; u < 4; ++u) {
      int seg = (u << 8) + tid;
      int row = seg >> 3, ps = seg & 7;
      int phys = ps ^ (row & 7);
      uint4 h = make_uint4(0u, 0u, 0u, 0u), l = make_uint4(0u, 0u, 0u, 0u);
      if (row < L) {
        float4 a = *(const float4*)(Qb + (size_t)row * DM + c0 + (ps << 3));
        float4 c = *(const float4*)(Qb + (size_t)row * DM + c0 + (ps << 3) + 4);
        split8(a, c, h, l);
      }
      *(uint4*)(qh + row * 64 + (phys << 3)) = h;
      *(uint4*)(ql + row * 64 + (phys << 3)) = l;
      h = make_uint4(0u, 0u, 0u, 0u); l = make_uint4(0u, 0u, 0u, 0u);
      if (row < S) {
        float4 a = *(const float4*)(Kb + (size_t)row * DM + c0 + (ps << 3));
        float4 c = *(const float4*)(Kb + (size_t)row * DM + c0 + (ps << 3) + 4);
        split8(a, c, h, l);
      }
      *(uint4*)(kh + row * 64 + (phys << 3)) = h;
      *(uint4*)(kl + row * 64 + (phys << 3)) = l;
    }
    __syncthreads();
#pragma unroll
    for (int ks = 0; ks < 2; ++ks) {
      bf16x8 aqh[4], aql[4], bkh[4], bkl[4];
#pragma unroll
      for (int i = 0; i < 4; ++i) {
        int ra = wm + i * 16 + (lane & 15);
        int sa = ((ks << 2) + (lane >> 4)) ^ (ra & 7);
        aqh[i] = *(const bf16x8*)(qh + ra * 64 + (sa << 3));
        aql[i] = *(const bf16x8*)(ql + ra * 64 + (sa << 3));
        int rb = wn + i * 16 + (lane & 15);
        int sb = ((ks << 2) + (lane >> 4)) ^ (rb & 7);
        bkh[i] = *(const bf16x8*)(kh + rb * 64 + (sb << 3));
        bkl[i] = *(const bf16x8*)(kl + rb * 64 + (sb << 3));
      }
#pragma unroll
      for (int i = 0; i < 4; ++i)
#pragma unroll
        for (int j = 0; j < 4; ++j) {
          acc[i][j] = __builtin_amdgcn_mfma_f32_16x16x32_bf16(aqh[i], bkh[j], acc[i][j], 0, 0, 0);
          acc[i][j] = __builtin_amdgcn_mfma_f32_16x16x32_bf16(aql[i], bkh[j], acc[i][j], 0, 0, 0);
          acc[i][j] = __builtin_amdgcn_mfma_f32_16x16x32_bf16(aqh[i], bkl[j], acc[i][j], 0, 0, 0);
        }
    }
    __syncthreads();
  }
#pragma unroll
  for (int i = 0; i < 4; ++i)
#pragma unroll
    for (int j = 0; j < 4; ++j)
#pragma unroll
      for (int q = 0; q < 4; ++q)
        G[(wm + i * 16 + ((lane >> 4) << 2) + q) * 128 + wn + j * 16 + (lane & 15)] = acc[i][j][q];
  __syncthreads();
  float s = 0.f;
  if (tid < L) {
    for (int t = 0; t < L; ++t) {
      int r = t - tid; if (r < 0) r += L;
      s += G[t * 128 + r];
    }
    s *= (1.f / 256.f);
  }
  __syncthreads();   // all reads of G done before smem reuse

  // fused top-k + softmax (reuse smem front)
  float* vals = (float*)smem;            // [128]
  float* rv   = vals + 128;              // [128]
  int*   ri   = (int*)(rv + 128);        // [128]
  float* selv = (float*)(ri + 128);      // [16]
  int*   seli = (int*)(selv + 16);       // [16]
  if (tid < 128) vals[tid] = (tid < L) ? s : -3e38f;
  __syncthreads();
  for (int it = 0; it < TK; ++it) {
    if (tid < 128) { rv[tid] = vals[tid]; ri[tid] = tid; }
    __syncthreads();
    for (int off = 64; off >= 1; off >>= 1) {
      if (tid < off) {
        float v2 = rv[tid + off]; int i2 = ri[tid + off];
        if (v2 > rv[tid] || (v2 == rv[tid] && i2 < ri[tid])) { rv[tid] = v2; ri[tid] = i2; }
      }
      __syncthreads();
    }
    if (tid == 0) { selv[it] = rv[0]; seli[it] = ri[0]; vals[ri[0]] = -3e38f; }
    __syncthreads();
  }
  if (tid == 0) {
    float mxv = selv[0];
    float e[16]; float sum = 0.f;
    for (int j = 0; j < TK; ++j) { e[j] = expf(selv[j] - mxv); sum += e[j]; }
    float inv = 1.f / sum;
    for (int j = 0; j < TK; ++j) {
      wout[(size_t)b * 16 + j] = e[j] * inv;
      dout[(size_t)b * 16 + j] = seli[j];
    }
  }
}

// ---------------- weighted circular gather: LDS-staged V per (b, channel-half) ----------------
__global__ __launch_bounds__(256)
void k_gather2(const float* __restrict__ V, const float* __restrict__ wtop,
               const int* __restrict__ dtop, float* __restrict__ out,
               int L, int S, int TK) {
  __shared__ float Vs[LD * 128];        // <= 59,392 B
  __shared__ float wsm[16];
  __shared__ int   dsm[16];
  int b = blockIdx.x >> 1, half = blockIdx.x & 1;
  int tid = threadIdx.x;
  if (tid < TK) { wsm[tid] = wtop[(size_t)b * 16 + tid]; dsm[tid] = dtop[(size_t)b * 16 + tid]; }
  const float* Vb = V + (size_t)b * S * DM + half * 128;
  for (int i = tid; i < S * 32; i += 256) {
    int r = i >> 5, c4 = (i & 31) << 2;
    *(float4*)&Vs[r * 128 + c4] = *(const float4*)(Vb + (size_t)r * DM + c4);
  }
  __syncthreads();
  int c = tid & 127, lh = tid >> 7;
  float* ob = out + (size_t)b * L * DM + half * 128 + c;
  for (int l = lh; l < L; l += 2) {
    float acc = 0.f;
    for (int j = 0; j < TK; ++j) {
      int r = l + dsm[j]; if (r >= L) r -= L;
      if (r < S) acc += wsm[j] * Vs[r * 128 + c];
    }
    ob[(size_t)l * DM] = acc;
  }
}

// ---------------- series_decomp ----------------
template <int MOUT>
__global__ __launch_bounds__(128)
void k_decomp(const float* __restrict__ X, const float* __restrict__ Y,
              float* __restrict__ out, float* __restrict__ mout, int L) {
  int b = blockIdx.x >> 1, half = blockIdx.x & 1;
  __shared__ float tmp[LD * 128];
  size_t base = (size_t)b * L * DM + half * 128;
  for (int i = threadIdx.x; i < L * 128; i += 128) {
    int t = i >> 7, cc = i & 127;
    size_t gi = base + (size_t)t * DM + cc;
    tmp[i] = X[gi] + Y[gi];
  }
  __syncthreads();
  int tid = threadIdx.x;
  float s = 0.f;
  for (int d = -12; d <= 12; ++d) { int t2 = d < 0 ? 0 : d; s += tmp[t2 * 128 + tid]; }
  for (int t = 0; t < L; ++t) {
    float m = s * (1.f / 25.f);
    size_t gi = base + (size_t)t * DM + tid;
    out[gi] = tmp[t * 128 + tid] - m;
    if (MOUT) mout[gi] = m;
    int ai = t + 13; if (ai > L - 1) ai = L - 1;
    int si = t - 12; if (si < 0) si = 0;
    s += tmp[ai * 128 + tid] - tmp[si * 128 + tid];
  }
}

// ---------------- my_layernorm ----------------
__global__ __launch_bounds__(256)
void k_lnorm(const float* __restrict__ X, const float* __restrict__ g,
             float* __restrict__ out, int L) {
  int b = blockIdx.x;
  __shared__ float mu_s[LD], inv_s[LD];
  size_t base = (size_t)b * L * DM;
  int wv = threadIdx.x >> 6, lane = threadIdx.x & 63;
  for (int t = wv; t < L; t += 4) {
    float s = 0.f, s2 = 0.f;
#pragma unroll
    for (int qd = 0; qd < 4; ++qd) {
      float val = X[base + (size_t)t * DM + lane + 64 * qd];
      s += val; s2 += val * val;
    }
    for (int off = 32; off; off >>= 1) { s += __shfl_xor(s, off); s2 += __shfl_xor(s2, off); }
    if (lane == 0) {
      float mu = s * (1.f / 256.f);
      mu_s[t] = mu;
      inv_s[t] = rsqrtf(s2 * (1.f / 256.f) - mu * mu + 1e-5f);
    }
  }
  __syncthreads();
  int c = threadIdx.x;
  float gc = g[c];
  float sm = 0.f;
  for (int t = 0; t < L; ++t) sm += (X[base + (size_t)t * DM + c] - mu_s[t]) * inv_s[t];
  float mn = sm / (float)L;
  for (int t = 0; t < L; ++t) {
    float xn = (X[base + (size_t)t * DM + c] - mu_s[t]) * inv_s[t];
    out[base + (size_t)t * DM + c] = gc * (xn - mn);
  }
}

// ---------------- trend conv ----------------
__global__ __launch_bounds__(256)
void k_trendconv(const float* __restrict__ T, const float* __restrict__ Wt,
                 float* __restrict__ trend, int L) {
  int bl = blockIdx.x;
  int b = bl / L, l = bl - b * L;
  int c = threadIdx.x;
  int lm = (l == 0) ? L - 1 : l - 1;
  int lp = (l == L - 1) ? 0 : l + 1;
  size_t base = (size_t)b * L * DM;
  float xm = T[base + (size_t)lm * DM + c];
  float x0 = T[base + (size_t)l * DM + c];
  float xp = T[base + (size_t)lp * DM + c];
  __shared__ float red[5][256];
#pragma unroll
  for (int o = 0; o < 5; ++o)
    red[o][c] = xm * Wt[o * 768 + c * 3 + 0] + x0 * Wt[o * 768 + c * 3 + 1] + xp * Wt[o * 768 + c * 3 + 2];
  __syncthreads();
  for (int off = 128; off >= 1; off >>= 1) {
    if (c < off) {
#pragma unroll
      for (int o = 0; o < 5; ++o) red[o][c] += red[o][c + off];
    }
    __syncthreads();
  }
  if (c < 5) trend[((size_t)b * L + l) * 5 + c] += red[c][0];
}

// ---------------- final head ----------------
__global__ __launch_bounds__(256)
void k_final(const float* __restrict__ dec, const float* __restrict__ trend,
             const float* __restrict__ projW, const float* __restrict__ projb,
             const float* __restrict__ bng, const float* __restrict__ bnb,
             const float* __restrict__ bnrm, const float* __restrict__ bnrv,
             const float* __restrict__ fcW, const float* __restrict__ fcb,
             float* __restrict__ outp) {
  int b = blockIdx.x, c = threadIdx.x;
  __shared__ float red[5][256];
  float xv = dec[((size_t)b * LD + (LD - 1)) * DM + c];
#pragma unroll
  for (int o = 0; o < 5; ++o) red[o][c] = xv * projW[o * 256 + c];
  __syncthreads();
  for (int off = 128; off >= 1; off >>= 1) {
    if (c < off) {
#pragma unroll
      for (int o = 0; o < 5; ++o) red[o][c] += red[o][c + off];
    }
    __syncthreads();
  }
  if (c == 0) {
    float acc = fcb[0];
    for (int j = 0; j < 20; ++j) {
      int m5 = j % 5;
      float last = trend[((size_t)b * LD + (LD - 1)) * 5 + m5] + red[m5][0] + projb[m5];
      float h = (last - bnrm[j]) * rsqrtf(bnrv[j] + 1e-5f) * bng[j] + bnb[j];
      acc += h * fcW[j];
    }
    outp[b] = acc;
  }
}

// ================================ host ================================
extern "C" void kernel_launch(void* const* d_in, const int* in_sizes, int n_in,
                              void* d_out, int out_size, void* d_ws, size_t ws_size,
                              hipStream_t stream) {
  const float* x      = (const float*)d_in[0];
  const float* we_enc = (const float*)d_in[1];
  const float* we_dec = (const float*)d_in[2];
  const float* enc_Wq = (const float*)d_in[3];
  const float* enc_bq = (const float*)d_in[4];
  const float* enc_Wk = (const float*)d_in[5];
  const float* enc_bk = (const float*)d_in[6];
  const float* enc_Wv = (const float*)d_in[7];
  const float* enc_bv = (const float*)d_in[8];
  const float* enc_Wo = (const float*)d_in[9];
  const float* enc_bo = (const float*)d_in[10];
  const float* enc_W1 = (const float*)d_in[11];
  const float* enc_W2 = (const float*)d_in[12];
  const float* enc_g  = (const float*)d_in[13];
  const float* sWq = (const float*)d_in[15]; const float* sbq = (const float*)d_in[16];
  const float* sWk = (const float*)d_in[17]; const float* sbk = (const float*)d_in[18];
  const float* sWv = (const float*)d_in[19]; const float* sbv = (const float*)d_in[20];
  const float* sWo = (const float*)d_in[21]; const float* sbo = (const float*)d_in[22];
  const float* cWq = (const float*)d_in[23]; const float* cbq = (const float*)d_in[24];
  const float* cWk = (const float*)d_in[25]; const float* cbk = (const float*)d_in[26];
  const float* cWv = (const float*)d_in[27]; const float* cbv = (const float*)d_in[28];
  const float* cWo = (const float*)d_in[29]; const float* cbo = (const float*)d_in[30];
  const float* dW1 = (const float*)d_in[31]; const float* dW2 = (const float*)d_in[32];
  const float* dWt = (const float*)d_in[33];
  const float* dec_g  = (const float*)d_in[34];
  const float* projW = (const float*)d_in[36]; const float* projb = (const float*)d_in[37];
  const float* bng = (const float*)d_in[38]; const float* bnb = (const float*)d_in[39];
  const float* bnrm = (const float*)d_in[40]; const float* bnrv = (const float*)d_in[41];
  const float* fcW = (const float*)d_in[42]; const float* fcb = (const float*)d_in[43];
  (void)in_sizes; (void)n_in; (void)out_size; (void)d_ws; (void)ws_size;
  float* outp = (float*)d_out;

  void* symaddr = nullptr;
  if (hipGetSymbolAddress(&symaddr, HIP_SYMBOL(g_ws)) != hipSuccess || !symaddr) return;
  unsigned char* base = (unsigned char*)symaddr;
  float* enc   = (float*)(base + o_enc);
  float* dec   = (float*)(base + o_dec);
  float* q     = (float*)(base + o_q);
  float* kbuf  = (float*)(base + o_kbuf);
  float* spad  = (float*)(base + o_spad);
  float* trend = (float*)(base + o_trend);
  float* wtop  = (float*)(base + o_wtop);
  int*   dtop  = (int*)(base + o_dtop);
  unsigned short* whi = (unsigned short*)(base + o_whi);
  unsigned short* wlo = (unsigned short*)(base + o_wlo);

  const int ME = B_ * LE;
  const int MD = B_ * LD;

  auto cast = [&](const float* s, size_t off, int n) {
    k_cast_split<<<n / 1024, 256, 0, stream>>>(s, whi + off, wlo + off, n);
  };
  cast(enc_Wq, wq_e, 131072);  cast(enc_Wk, wk_e, 131072);
  cast(enc_Wv, wv_e, 131072);  cast(enc_Wo, wo_e, 131072);
  cast(enc_W1, w1_e, 524288);  cast(enc_W2, w2_e, 524288);
  cast(sWq, swq_e, 131072);    cast(sWk, swk_e, 131072);
  cast(sWv, swv_e, 131072);    cast(sWo, swo_e, 131072);
  cast(cWq, cwq_e, 131072);    cast(cWk, cwk_e, 131072);
  cast(cWv, cwv_e, 131072);    cast(cWo, cwo_e, 131072);
  cast(dW1, dw1_e, 524288);    cast(dW2, dw2_e, 524288);

  auto gemm = [&](const float* X, size_t woff, const float* bias, float* C,
                  int M, int N, int K, bool relu) {
    int nwg = (M >> 7) * (N >> 7);
    if (relu) k_gemm_split<true ><<<nwg, 256, 0, stream>>>(X, whi + woff, wlo + woff, bias, C, M, N, K);
    else      k_gemm_split<false><<<nwg, 256, 0, stream>>>(X, whi + woff, wlo + woff, bias, C, M, N, K);
  };
  auto ffn = [&](const float* xb, int M, size_t w1, size_t w2) {
    int done = 0;
    while (done < M) {
      int mc = (M - done < 29696) ? (M - done) : 29696;
      gemm(xb + (size_t)done * DM, w1, nullptr, q, mc, DFF, DM, true);
      gemm(q, w2, nullptr, kbuf + (size_t)done * DM, mc, DM, DFF, false);
      done += mc;
    }
  };
  auto attn = [&](const float* src_q, int Lq, const float* src_kv, int S,
                  size_t wq, size_t wk, size_t wv2, size_t wo2,
                  const float* bq, const float* bk, const float* bv, const float* bo, int TK) {
    int Mq = B_ * Lq, Ms = B_ * S;
    gemm(src_q,  wq,  bq, q,    Mq, DM, DM, false);
    gemm(src_kv, wk,  bk, kbuf, Ms, DM, DM, false);
    k_corr_split<<<B_, 256, 0, stream>>>(q, kbuf, wtop, dtop, Lq, S, TK);
    gemm(src_kv, wv2, bv, q, Ms, DM, DM, false);        // V into q (Q dead after corr)
    k_gather2<<<2 * B_, 256, 0, stream>>>(q, wtop, dtop, kbuf, Lq, S, TK);
    gemm(kbuf, wo2, bo, q, Mq, DM, DM, false);          // attn out -> q
  };

  // ---- preprocess + embeddings ----
  k_pre<<<B_, 128, 0, stream>>>(x, spad, trend);
  k_conv3<<<B_, 256, 0, stream>>>(x, we_enc, enc, LE);
  k_conv3<<<B_, 256, 0, stream>>>(spad, we_dec, dec, LD);

  // ---- encoder ----
  for (int i = 0; i < 2; ++i) {
    size_t wofs = (size_t)i * 65536, b_ = (size_t)i * DM, f1 = (size_t)i * 262144;
    attn(enc, LE, enc, LE, wq_e + wofs, wk_e + wofs, wv_e + wofs, wo_e + wofs,
         enc_bq + b_, enc_bk + b_, enc_bv + b_, enc_bo + b_, 13);
    k_decomp<0><<<2 * B_, 128, 0, stream>>>(enc, q, enc, nullptr, LE);
    ffn(enc, ME, w1_e + f1, w2_e + f1);
    k_decomp<0><<<2 * B_, 128, 0, stream>>>(enc, kbuf, enc, nullptr, LE);
  }
  k_lnorm<<<B_, 256, 0, stream>>>(enc, enc_g, enc, LE);

  // ---- decoder ----
  for (int i = 0; i < 2; ++i) {
    size_t wofs = (size_t)i * 65536, b_ = (size_t)i * DM, f1 = (size_t)i * 262144;
    const float* Wt_i = dWt + (size_t)i * 5 * DM * 3;
    attn(dec, LD, dec, LD, swq_e + wofs, swk_e + wofs, swv_e + wofs, swo_e + wofs,
         sbq + b_, sbk + b_, sbv + b_, sbo + b_, 14);
    k_decomp<1><<<2 * B_, 128, 0, stream>>>(dec, q, dec, kbuf, LD);
    k_trendconv<<<B_ * LD, 256, 0, stream>>>(kbuf, Wt_i, trend, LD);
    attn(dec, LD, enc, LE, cwq_e + wofs, cwk_e + wofs, cwv_e + wofs, cwo_e + wofs,
         cbq + b_, cbk + b_, cbv + b_, cbo + b_, 14);
    k_decomp<1><<<2 * B_, 128, 0, stream>>>(dec, q, dec, kbuf, LD);
    k_trendconv<<<B_ * LD, 256, 0, stream>>>(kbuf, Wt_i, trend, LD);
    ffn(dec, MD, dw1_e + f1, dw2_e + f1);
    k_decomp<1><<<2 * B_, 128, 0, stream>>>(dec, kbuf, dec, q, LD);
    k_trendconv<<<B_ * LD, 256, 0, stream>>>(q, Wt_i, trend, LD);
  }
  k_lnorm<<<B_, 256, 0, stream>>>(dec, dec_g, dec, LD);

  // ---- output head ----
  k_final<<<B_, 256, 0, stream>>>(dec, trend, projW, projb, bng, bnb, bnrm, bnrv, fcW, fcb, outp);
}

// Round 6
// 6968.397 us; speedup vs baseline: 1.1838x; 1.1838x over previous
//
#include <hip/hip_runtime.h>
#include <hip/hip_bf16.h>
#include <cstdint>
#include <cstddef>

// Autoformer forward, MI355X. Round 6: r5 (passing) with
//   - gather: round-4 high-occupancy form + XCD-affinity remap (batch -> one XCD's L2)
//   - trendconv: 1 block/batch, reg-held weights, wave butterfly reduce
#define B_   1024
#define LE   96
#define LD   116
#define DM   256
#define DFF  1024

typedef __attribute__((ext_vector_type(8))) short bf16x8;
typedef __attribute__((ext_vector_type(4))) float f32x4;

static __device__ __forceinline__ unsigned short f2b(float f) {
  __hip_bfloat16 h = __float2bfloat16(f);
  return *reinterpret_cast<unsigned short*>(&h);
}
static __device__ __forceinline__ float asf(unsigned int u) { return __uint_as_float(u); }

// split 8 f32 -> 8 bf16 hi + 8 bf16 lo (x = hi + lo, residual ~2^-18 relative)
static __device__ __forceinline__ void split8(float4 a, float4 b, uint4& h4, uint4& l4) {
  float f[8] = {a.x, a.y, a.z, a.w, b.x, b.y, b.z, b.w};
  unsigned int hp[4], lp[4];
#pragma unroll
  for (int j = 0; j < 4; ++j) {
    unsigned short h0 = f2b(f[2 * j]);
    unsigned short h1 = f2b(f[2 * j + 1]);
    float r0 = f[2 * j]     - asf((unsigned int)h0 << 16);
    float r1 = f[2 * j + 1] - asf((unsigned int)h1 << 16);
    hp[j] = (unsigned int)h0 | ((unsigned int)h1 << 16);
    lp[j] = (unsigned int)f2b(r0) | ((unsigned int)f2b(r1) << 16);
  }
  h4 = make_uint4(hp[0], hp[1], hp[2], hp[3]);
  l4 = make_uint4(lp[0], lp[1], lp[2], lp[3]);
}

typedef const __attribute__((address_space(1))) void* gas_ptr;
typedef __attribute__((address_space(3))) void* las_ptr;
static __device__ __forceinline__ void gload16(const void* g, void* l) {
  __builtin_amdgcn_global_load_lds((gas_ptr)g, (las_ptr)l, 16, 0, 0);
}

// ---------------- workspace (static; ws_size-independent) ----------------
#define NE_ ((size_t)B_ * LE * DM)
#define ND_ ((size_t)B_ * LD * DM)
#define NS_ ((size_t)B_ * LD * 5)
#define NW_ ((size_t)B_ * 16)
#define WBF_ 3670016

static constexpr size_t o_enc   = 0;
static constexpr size_t o_dec   = o_enc   + NE_ * 4;
static constexpr size_t o_q     = o_dec   + ND_ * 4;
static constexpr size_t o_kbuf  = o_q     + ND_ * 4;
static constexpr size_t o_spad  = o_kbuf  + ND_ * 4;
static constexpr size_t o_trend = o_spad  + NS_ * 4;
static constexpr size_t o_wtop  = o_trend + NS_ * 4;
static constexpr size_t o_dtop  = o_wtop  + NW_ * 4;
static constexpr size_t o_whi   = o_dtop  + NW_ * 4;
static constexpr size_t o_wlo   = o_whi   + (size_t)WBF_ * 2;
static constexpr size_t WS_TOTAL = o_wlo  + (size_t)WBF_ * 2;

__device__ __align__(256) unsigned char g_ws[WS_TOTAL];

static constexpr size_t wq_e = 0, wk_e = 131072, wv_e = 262144, wo_e = 393216;
static constexpr size_t w1_e = 524288, w2_e = 1048576;
static constexpr size_t swq_e = 1572864, swk_e = 1703936, swv_e = 1835008, swo_e = 1966080;
static constexpr size_t cwq_e = 2097152, cwk_e = 2228224, cwv_e = 2359296, cwo_e = 2490368;
static constexpr size_t dw1_e = 2621440, dw2_e = 3145728;

// ---------------- weight split cast ----------------
__global__ __launch_bounds__(256)
void k_cast_split(const float* __restrict__ in, unsigned short* __restrict__ hi,
                  unsigned short* __restrict__ lo, int n) {
  int i = (blockIdx.x * 256 + threadIdx.x) * 4;
  if (i < n) {
    float4 v = *(const float4*)(in + i);
    unsigned int hp[2], lp[2];
    float f[4] = {v.x, v.y, v.z, v.w};
#pragma unroll
    for (int j = 0; j < 2; ++j) {
      unsigned short h0 = f2b(f[2 * j]);
      unsigned short h1 = f2b(f[2 * j + 1]);
      float r0 = f[2 * j]     - asf((unsigned int)h0 << 16);
      float r1 = f[2 * j + 1] - asf((unsigned int)h1 << 16);
      hp[j] = (unsigned int)h0 | ((unsigned int)h1 << 16);
      lp[j] = (unsigned int)f2b(r0) | ((unsigned int)f2b(r1) << 16);
    }
    *(uint2*)(hi + i) = make_uint2(hp[0], hp[1]);
    *(uint2*)(lo + i) = make_uint2(lp[0], lp[1]);
  }
}

// ---------------- preprocess ----------------
__global__ __launch_bounds__(128)
void k_pre(const float* __restrict__ x, float* __restrict__ spad, float* __restrict__ trend) {
  int b = blockIdx.x;
  __shared__ float xs[LE * 5];
  __shared__ float mx[5];
  const float* xb = x + (size_t)b * LE * 5;
  for (int i = threadIdx.x; i < LE * 5; i += 128) xs[i] = xb[i];
  __syncthreads();
  if (threadIdx.x < 5) {
    float s = 0.f;
    for (int t = 0; t < LE; ++t) s += xs[t * 5 + threadIdx.x];
    mx[threadIdx.x] = s * (1.f / 96.f);
  }
  __syncthreads();
  float* spb = spad + (size_t)b * LD * 5;
  float* trb = trend + (size_t)b * LD * 5;
  for (int i = threadIdx.x; i < LE * 5; i += 128) {
    int t = i / 5, c = i % 5;
    float s = 0.f;
    for (int d = -12; d <= 12; ++d) {
      int tt = t + d; tt = tt < 0 ? 0 : (tt > LE - 1 ? LE - 1 : tt);
      s += xs[tt * 5 + c];
    }
    float m = s * (1.f / 25.f);
    trb[t * 5 + c] = m;
    spb[(t + 20) * 5 + c] = xs[i] - m;
  }
  for (int i = threadIdx.x; i < 20 * 5; i += 128) {
    int t = i / 5, c = i % 5;
    spb[t * 5 + c] = 0.f;
    trb[(LE + t) * 5 + c] = mx[c];
  }
}

// ---------------- circular 3-tap conv ----------------
__global__ __launch_bounds__(256)
void k_conv3(const float* __restrict__ xin, const float* __restrict__ W,
             float* __restrict__ out, int L) {
  int b = blockIdx.x, o = threadIdx.x;
  __shared__ float xs[LD * 5];
  const float* xb = xin + (size_t)b * L * 5;
  for (int i = o; i < L * 5; i += 256) xs[i] = xb[i];
  __syncthreads();
  float w[15];
#pragma unroll
  for (int j = 0; j < 15; ++j) w[j] = W[o * 15 + j];
  float* ob = out + (size_t)b * L * DM;
  for (int l = 0; l < L; ++l) {
    int lm = (l == 0) ? L - 1 : l - 1;
    int lp = (l == L - 1) ? 0 : l + 1;
    float acc = 0.f;
#pragma unroll
    for (int c = 0; c < 5; ++c)
      acc += xs[lm * 5 + c] * w[c * 3] + xs[l * 5 + c] * w[c * 3 + 1] + xs[lp * 5 + c] * w[c * 3 + 2];
    ob[(size_t)l * DM + o] = acc;
  }
}

// ---------------- split-bf16 MFMA GEMM (f32-accurate) ----------------
template <bool RELU>
__global__ __launch_bounds__(256)
void k_gemm_split(const float* __restrict__ X,
                  const unsigned short* __restrict__ Whi, const unsigned short* __restrict__ Wlo,
                  const float* __restrict__ bias, float* __restrict__ C,
                  int M, int N, int K) {
  __shared__ __align__(16) unsigned short Xh[4096], Xl[4096], Wh[4096], Wl[4096];
  const int nwg = gridDim.x, bid = blockIdx.x;
  const int wg = (bid & 7) * (nwg >> 3) + (bid >> 3);   // XCD swizzle (nwg%8==0 here)
  const int NT = N >> 7;
  const int mt = wg / NT, nt = wg % NT;                 // nt-fast: X stripe reused on-XCD
  const int m0 = mt << 7, n0 = nt << 7;
  const int tid = threadIdx.x, lane = tid & 63, wv = tid >> 6;
  const int wm = (wv >> 1) << 6, wn = (wv & 1) << 6;

  f32x4 acc[4][4];
#pragma unroll
  for (int i = 0; i < 4; ++i)
#pragma unroll
    for (int j = 0; j < 4; ++j) acc[i][j] = (f32x4){0.f, 0.f, 0.f, 0.f};

  const int r0 = tid >> 2,        ls0 = (tid & 3) ^ ((r0 >> 1) & 3);
  const int r1 = 64 + (tid >> 2), ls1 = (tid & 3) ^ ((r1 >> 1) & 3);
  const unsigned short* wh0 = Whi + (size_t)(n0 + r0) * K + (ls0 << 3);
  const unsigned short* wh1 = Whi + (size_t)(n0 + r1) * K + (ls1 << 3);
  const unsigned short* wl0 = Wlo + (size_t)(n0 + r0) * K + (ls0 << 3);
  const unsigned short* wl1 = Wlo + (size_t)(n0 + r1) * K + (ls1 << 3);
  unsigned short* lwh0 = Wh + ((tid & ~63) << 3);
  unsigned short* lwh1 = Wh + 2048 + ((tid & ~63) << 3);
  unsigned short* lwl0 = Wl + ((tid & ~63) << 3);
  unsigned short* lwl1 = Wl + 2048 + ((tid & ~63) << 3);

  const int xrow0 = tid >> 2, xpart = tid & 3;
  const int xrow1 = 64 + xrow0;
  const float* xp0 = X + (size_t)(m0 + xrow0) * K + (xpart << 3);
  const float* xp1 = X + (size_t)(m0 + xrow1) * K + (xpart << 3);
  const int xph0 = xpart ^ ((xrow0 >> 1) & 3);
  const int xph1 = xpart ^ ((xrow1 >> 1) & 3);
  unsigned short* xh0d = Xh + xrow0 * 32 + (xph0 << 3);
  unsigned short* xl0d = Xl + xrow0 * 32 + (xph0 << 3);
  unsigned short* xh1d = Xh + xrow1 * 32 + (xph1 << 3);
  unsigned short* xl1d = Xl + xrow1 * 32 + (xph1 << 3);

  for (int k0 = 0; k0 < K; k0 += 32) {
    gload16(wh0 + k0, lwh0);
    gload16(wh1 + k0, lwh1);
    gload16(wl0 + k0, lwl0);
    gload16(wl1 + k0, lwl1);
    {
      float4 a0 = *(const float4*)(xp0 + k0);
      float4 b0 = *(const float4*)(xp0 + k0 + 4);
      float4 a1 = *(const float4*)(xp1 + k0);
      float4 b1 = *(const float4*)(xp1 + k0 + 4);
      uint4 h, l;
      split8(a0, b0, h, l);
      *(uint4*)xh0d = h; *(uint4*)xl0d = l;
      split8(a1, b1, h, l);
      *(uint4*)xh1d = h; *(uint4*)xl1d = l;
    }
    __syncthreads();
    bf16x8 ah[4], al[4], bh[4], bl[4];
#pragma unroll
    for (int i = 0; i < 4; ++i) {
      int ra = wm + i * 16 + (lane & 15);
      int sa = (lane >> 4) ^ ((ra >> 1) & 3);
      ah[i] = *(const bf16x8*)(Xh + ra * 32 + (sa << 3));
      al[i] = *(const bf16x8*)(Xl + ra * 32 + (sa << 3));
      int rb = wn + i * 16 + (lane & 15);
      int sb = (lane >> 4) ^ ((rb >> 1) & 3);
      bh[i] = *(const bf16x8*)(Wh + rb * 32 + (sb << 3));
      bl[i] = *(const bf16x8*)(Wl + rb * 32 + (sb << 3));
    }
#pragma unroll
    for (int i = 0; i < 4; ++i)
#pragma unroll
      for (int j = 0; j < 4; ++j) {
        acc[i][j] = __builtin_amdgcn_mfma_f32_16x16x32_bf16(ah[i], bh[j], acc[i][j], 0, 0, 0);
        acc[i][j] = __builtin_amdgcn_mfma_f32_16x16x32_bf16(al[i], bh[j], acc[i][j], 0, 0, 0);
        acc[i][j] = __builtin_amdgcn_mfma_f32_16x16x32_bf16(ah[i], bl[j], acc[i][j], 0, 0, 0);
      }
    __syncthreads();
  }

  const int col_base = n0 + wn + (lane & 15);
  const int row_base = m0 + wm + ((lane >> 4) << 2);
#pragma unroll
  for (int j = 0; j < 4; ++j) {
    int col = col_base + j * 16;
    float bv = bias ? bias[col] : 0.f;
#pragma unroll
    for (int i = 0; i < 4; ++i) {
      int rb2 = row_base + i * 16;
#pragma unroll
      for (int q = 0; q < 4; ++q) {
        float o = acc[i][j][q] + bv;
        if (RELU) o = fmaxf(o, 0.f);
        C[(size_t)(rb2 + q) * N + col] = o;
      }
    }
  }
}

// ---------------- corr (split-bf16 MFMA Gram) + fused top-k/softmax ----------------
__global__ __launch_bounds__(256)
void k_corr_split(const float* __restrict__ Q, const float* __restrict__ Kp,
                  float* __restrict__ wout, int* __restrict__ dout,
                  int L, int S, int TK) {
  __shared__ __align__(16) unsigned char smem[65536];
  unsigned short* qh = (unsigned short*)smem;   // [128][64]
  unsigned short* ql = qh + 8192;
  unsigned short* kh = ql + 8192;
  unsigned short* kl = kh + 8192;
  float* G = (float*)smem;                      // [128][128] overlays after K-loop
  int b = blockIdx.x, tid = threadIdx.x, lane = tid & 63, wv = tid >> 6;
  int wm = (wv >> 1) << 6, wn = (wv & 1) << 6;
  const float* Qb = Q + (size_t)b * L * DM;
  const float* Kb = Kp + (size_t)b * S * DM;
  f32x4 acc[4][4];
#pragma unroll
  for (int i = 0; i < 4; ++i)
#pragma unroll
    for (int j = 0; j < 4; ++j) acc[i][j] = (f32x4){0.f, 0.f, 0.f, 0.f};

  for (int c0 = 0; c0 < DM; c0 += 64) {
#pragma unroll
    for (int u = 0; u < 4; ++u) {
      int seg = (u << 8) + tid;
      int row = seg >> 3, ps = seg & 7;
      int phys = ps ^ (row & 7);
      uint4 h = make_uint4(0u, 0u, 0u, 0u), l = make_uint4(0u, 0u, 0u, 0u);
      if (row < L) {
        float4 a = *(const float4*)(Qb + (size_t)row * DM + c0 + (ps << 3));
        float4 c = *(const float4*)(Qb + (size_t)row * DM + c0 + (ps << 3) + 4);
        split8(a, c, h, l);
      }
      *(uint4*)(qh + row * 64 + (phys << 3)) = h;
      *(uint4*)(ql + row * 64 + (phys << 3)) = l;
      h = make_uint4(0u, 0u, 0u, 0u); l = make_uint4(0u, 0u, 0u, 0u);
      if (row < S) {
        float4 a = *(const float4*)(Kb + (size_t)row * DM + c0 + (ps << 3));
        float4 c = *(const float4*)(Kb + (size_t)row * DM + c0 + (ps << 3) + 4);
        split8(a, c, h, l);
      }
      *(uint4*)(kh + row * 64 + (phys << 3)) = h;
      *(uint4*)(kl + row * 64 + (phys << 3)) = l;
    }
    __syncthreads();
#pragma unroll
    for (int ks = 0; ks < 2; ++ks) {
      bf16x8 aqh[4], aql[4], bkh[4], bkl[4];
#pragma unroll
      for (int i = 0; i < 4; ++i) {
        int ra = wm + i * 16 + (lane & 15);
        int sa = ((ks << 2) + (lane >> 4)) ^ (ra & 7);
        aqh[i] = *(const bf16x8*)(qh + ra * 64 + (sa << 3));
        aql[i] = *(const bf16x8*)(ql + ra * 64 + (sa << 3));
        int rb = wn + i * 16 + (lane & 15);
        int sb = ((ks << 2) + (lane >> 4)) ^ (rb & 7);
        bkh[i] = *(const bf16x8*)(kh + rb * 64 + (sb << 3));
        bkl[i] = *(const bf16x8*)(kl + rb * 64 + (sb << 3));
      }
#pragma unroll
      for (int i = 0; i < 4; ++i)
#pragma unroll
        for (int j = 0; j < 4; ++j) {
          acc[i][j] = __builtin_amdgcn_mfma_f32_16x16x32_bf16(aqh[i], bkh[j], acc[i][j], 0, 0, 0);
          acc[i][j] = __builtin_amdgcn_mfma_f32_16x16x32_bf16(aql[i], bkh[j], acc[i][j], 0, 0, 0);
          acc[i][j] = __builtin_amdgcn_mfma_f32_16x16x32_bf16(aqh[i], bkl[j], acc[i][j], 0, 0, 0);
        }
    }
    __syncthreads();
  }
#pragma unroll
  for (int i = 0; i < 4; ++i)
#pragma unroll
    for (int j = 0; j < 4; ++j)
#pragma unroll
      for (int q = 0; q < 4; ++q)
        G[(wm + i * 16 + ((lane >> 4) << 2) + q) * 128 + wn + j * 16 + (lane & 15)] = acc[i][j][q];
  __syncthreads();
  float s = 0.f;
  if (tid < L) {
    for (int t = 0; t < L; ++t) {
      int r = t - tid; if (r < 0) r += L;
      s += G[t * 128 + r];
    }
    s *= (1.f / 256.f);
  }
  __syncthreads();   // all reads of G done before smem reuse

  float* vals = (float*)smem;            // [128]
  float* rv   = vals + 128;              // [128]
  int*   ri   = (int*)(rv + 128);        // [128]
  float* selv = (float*)(ri + 128);      // [16]
  int*   seli = (int*)(selv + 16);       // [16]
  if (tid < 128) vals[tid] = (tid < L) ? s : -3e38f;
  __syncthreads();
  for (int it = 0; it < TK; ++it) {
    if (tid < 128) { rv[tid] = vals[tid]; ri[tid] = tid; }
    __syncthreads();
    for (int off = 64; off >= 1; off >>= 1) {
      if (tid < off) {
        float v2 = rv[tid + off]; int i2 = ri[tid + off];
        if (v2 > rv[tid] || (v2 == rv[tid] && i2 < ri[tid])) { rv[tid] = v2; ri[tid] = i2; }
      }
      __syncthreads();
    }
    if (tid == 0) { selv[it] = rv[0]; seli[it] = ri[0]; vals[ri[0]] = -3e38f; }
    __syncthreads();
  }
  if (tid == 0) {
    float mxv = selv[0];
    float e[16]; float sum = 0.f;
    for (int j = 0; j < TK; ++j) { e[j] = expf(selv[j] - mxv); sum += e[j]; }
    float inv = 1.f / sum;
    for (int j = 0; j < TK; ++j) {
      wout[(size_t)b * 16 + j] = e[j] * inv;
      dout[(size_t)b * 16 + j] = seli[j];
    }
  }
}

// ---------------- weighted circular gather, XCD-affine dispatch ----------------
// p = g*8 + (b%8); all L blocks of a batch go to one XCD -> V[b] L2-resident.
__global__ __launch_bounds__(256)
void k_gather3(const float* __restrict__ V, const float* __restrict__ wtop,
               const int* __restrict__ dtop, float* __restrict__ out,
               int L, int S, int TK) {
  int p = blockIdx.x;
  int g = p >> 3;
  int l = g % L;
  int b = (p & 7) + ((g / L) << 3);
  __shared__ float wsm[16];
  __shared__ int   dsm[16];
  if (threadIdx.x < TK) {
    wsm[threadIdx.x] = wtop[(size_t)b * 16 + threadIdx.x];
    dsm[threadIdx.x] = dtop[(size_t)b * 16 + threadIdx.x];
  }
  __syncthreads();
  int c = threadIdx.x;
  float acc = 0.f;
  for (int j = 0; j < TK; ++j) {
    int r = l + dsm[j]; if (r >= L) r -= L;
    if (r < S) acc += wsm[j] * V[((size_t)b * S + r) * DM + c];
  }
  out[((size_t)b * L + l) * DM + c] = acc;
}

// ---------------- series_decomp ----------------
template <int MOUT>
__global__ __launch_bounds__(128)
void k_decomp(const float* __restrict__ X, const float* __restrict__ Y,
              float* __restrict__ out, float* __restrict__ mout, int L) {
  int b = blockIdx.x >> 1, half = blockIdx.x & 1;
  __shared__ float tmp[LD * 128];
  size_t base = (size_t)b * L * DM + half * 128;
  for (int i = threadIdx.x; i < L * 128; i += 128) {
    int t = i >> 7, cc = i & 127;
    size_t gi = base + (size_t)t * DM + cc;
    tmp[i] = X[gi] + Y[gi];
  }
  __syncthreads();
  int tid = threadIdx.x;
  float s = 0.f;
  for (int d = -12; d <= 12; ++d) { int t2 = d < 0 ? 0 : d; s += tmp[t2 * 128 + tid]; }
  for (int t = 0; t < L; ++t) {
    float m = s * (1.f / 25.f);
    size_t gi = base + (size_t)t * DM + tid;
    out[gi] = tmp[t * 128 + tid] - m;
    if (MOUT) mout[gi] = m;
    int ai = t + 13; if (ai > L - 1) ai = L - 1;
    int si = t - 12; if (si < 0) si = 0;
    s += tmp[ai * 128 + tid] - tmp[si * 128 + tid];
  }
}

// ---------------- my_layernorm ----------------
__global__ __launch_bounds__(256)
void k_lnorm(const float* __restrict__ X, const float* __restrict__ g,
             float* __restrict__ out, int L) {
  int b = blockIdx.x;
  __shared__ float mu_s[LD], inv_s[LD];
  size_t base = (size_t)b * L * DM;
  int wv = threadIdx.x >> 6, lane = threadIdx.x & 63;
  for (int t = wv; t < L; t += 4) {
    float s = 0.f, s2 = 0.f;
#pragma unroll
    for (int qd = 0; qd < 4; ++qd) {
      float val = X[base + (size_t)t * DM + lane + 64 * qd];
      s += val; s2 += val * val;
    }
    for (int off = 32; off; off >>= 1) { s += __shfl_xor(s, off); s2 += __shfl_xor(s2, off); }
    if (lane == 0) {
      float mu = s * (1.f / 256.f);
      mu_s[t] = mu;
      inv_s[t] = rsqrtf(s2 * (1.f / 256.f) - mu * mu + 1e-5f);
    }
  }
  __syncthreads();
  int c = threadIdx.x;
  float gc = g[c];
  float sm = 0.f;
  for (int t = 0; t < L; ++t) sm += (X[base + (size_t)t * DM + c] - mu_s[t]) * inv_s[t];
  float mn = sm / (float)L;
  for (int t = 0; t < L; ++t) {
    float xn = (X[base + (size_t)t * DM + c] - mu_s[t]) * inv_s[t];
    out[base + (size_t)t * DM + c] = gc * (xn - mn);
  }
}

// ---------------- trend conv: 1 block/batch, reg weights, wave butterfly ----------------
__global__ __launch_bounds__(256)
void k_trendconv(const float* __restrict__ T, const float* __restrict__ Wt,
                 float* __restrict__ trend, int L) {
  int b = blockIdx.x;
  int tid = threadIdx.x, wv = tid >> 6, lane = tid & 63;
  int c0 = lane << 2;
  float w[5][3][4];
#pragma unroll
  for (int o = 0; o < 5; ++o)
#pragma unroll
    for (int k = 0; k < 4; ++k) {
      w[o][0][k] = Wt[o * 768 + (c0 + k) * 3 + 0];
      w[o][1][k] = Wt[o * 768 + (c0 + k) * 3 + 1];
      w[o][2][k] = Wt[o * 768 + (c0 + k) * 3 + 2];
    }
  size_t base = (size_t)b * L * DM;
  for (int l = wv; l < L; l += 4) {
    int lm = (l == 0) ? L - 1 : l - 1;
    int lp = (l == L - 1) ? 0 : l + 1;
    float4 xm = *(const float4*)(T + base + (size_t)lm * DM + c0);
    float4 x0 = *(const float4*)(T + base + (size_t)l  * DM + c0);
    float4 xp = *(const float4*)(T + base + (size_t)lp * DM + c0);
    float fm[4] = {xm.x, xm.y, xm.z, xm.w};
    float f0[4] = {x0.x, x0.y, x0.z, x0.w};
    float fp[4] = {xp.x, xp.y, xp.z, xp.w};
    float acc[5];
#pragma unroll
    for (int o = 0; o < 5; ++o) {
      float a = 0.f;
#pragma unroll
      for (int k = 0; k < 4; ++k)
        a += fm[k] * w[o][0][k] + f0[k] * w[o][1][k] + fp[k] * w[o][2][k];
      acc[o] = a;
    }
#pragma unroll
    for (int off = 32; off; off >>= 1)
#pragma unroll
      for (int o = 0; o < 5; ++o) acc[o] += __shfl_xor(acc[o], off);
    if (lane == 0) {
#pragma unroll
      for (int o = 0; o < 5; ++o)
        trend[((size_t)b * L + l) * 5 + o] += acc[o];
    }
  }
}

// ---------------- final head ----------------
__global__ __launch_bounds__(256)
void k_final(const float* __restrict__ dec, const float* __restrict__ trend,
             const float* __restrict__ projW, const float* __restrict__ projb,
             const float* __restrict__ bng, const float* __restrict__ bnb,
             const float* __restrict__ bnrm, const float* __restrict__ bnrv,
             const float* __restrict__ fcW, const float* __restrict__ fcb,
             float* __restrict__ outp) {
  int b = blockIdx.x, c = threadIdx.x;
  __shared__ float red[5][256];
  float xv = dec[((size_t)b * LD + (LD - 1)) * DM + c];
#pragma unroll
  for (int o = 0; o < 5; ++o) red[o][c] = xv * projW[o * 256 + c];
  __syncthreads();
  for (int off = 128; off >= 1; off >>= 1) {
    if (c < off) {
#pragma unroll
      for (int o = 0; o < 5; ++o) red[o][c] += red[o][c + off];
    }
    __syncthreads();
  }
  if (c == 0) {
    float acc = fcb[0];
    for (int j = 0; j < 20; ++j) {
      int m5 = j % 5;
      float last = trend[((size_t)b * LD + (LD - 1)) * 5 + m5] + red[m5][0] + projb[m5];
      float h = (last - bnrm[j]) * rsqrtf(bnrv[j] + 1e-5f) * bng[j] + bnb[j];
      acc += h * fcW[j];
    }
    outp[b] = acc;
  }
}

// ================================ host ================================
extern "C" void kernel_launch(void* const* d_in, const int* in_sizes, int n_in,
                              void* d_out, int out_size, void* d_ws, size_t ws_size,
                              hipStream_t stream) {
  const float* x      = (const float*)d_in[0];
  const float* we_enc = (const float*)d_in[1];
  const float* we_dec = (const float*)d_in[2];
  const float* enc_Wq = (const float*)d_in[3];
  const float* enc_bq = (const float*)d_in[4];
  const float* enc_Wk = (const float*)d_in[5];
  const float* enc_bk = (const float*)d_in[6];
  const float* enc_Wv = (const float*)d_in[7];
  const float* enc_bv = (const float*)d_in[8];
  const float* enc_Wo = (const float*)d_in[9];
  const float* enc_bo = (const float*)d_in[10];
  const float* enc_W1 = (const float*)d_in[11];
  const float* enc_W2 = (const float*)d_in[12];
  const float* enc_g  = (const float*)d_in[13];
  const float* sWq = (const float*)d_in[15]; const float* sbq = (const float*)d_in[16];
  const float* sWk = (const float*)d_in[17]; const float* sbk = (const float*)d_in[18];
  const float* sWv = (const float*)d_in[19]; const float* sbv = (const float*)d_in[20];
  const float* sWo = (const float*)d_in[21]; const float* sbo = (const float*)d_in[22];
  const float* cWq = (const float*)d_in[23]; const float* cbq = (const float*)d_in[24];
  const float* cWk = (const float*)d_in[25]; const float* cbk = (const float*)d_in[26];
  const float* cWv = (const float*)d_in[27]; const float* cbv = (const float*)d_in[28];
  const float* cWo = (const float*)d_in[29]; const float* cbo = (const float*)d_in[30];
  const float* dW1 = (const float*)d_in[31]; const float* dW2 = (const float*)d_in[32];
  const float* dWt = (const float*)d_in[33];
  const float* dec_g  = (const float*)d_in[34];
  const float* projW = (const float*)d_in[36]; const float* projb = (const float*)d_in[37];
  const float* bng = (const float*)d_in[38]; const float* bnb = (const float*)d_in[39];
  const float* bnrm = (const float*)d_in[40]; const float* bnrv = (const float*)d_in[41];
  const float* fcW = (const float*)d_in[42]; const float* fcb = (const float*)d_in[43];
  (void)in_sizes; (void)n_in; (void)out_size; (void)d_ws; (void)ws_size;
  float* outp = (float*)d_out;

  void* symaddr = nullptr;
  if (hipGetSymbolAddress(&symaddr, HIP_SYMBOL(g_ws)) != hipSuccess || !symaddr) return;
  unsigned char* base = (unsigned char*)symaddr;
  float* enc   = (float*)(base + o_enc);
  float* dec   = (float*)(base + o_dec);
  float* q     = (float*)(base + o_q);
  float* kbuf  = (float*)(base + o_kbuf);
  float* spad  = (float*)(base + o_spad);
  float* trend = (float*)(base + o_trend);
  float* wtop  = (float*)(base + o_wtop);
  int*   dtop  = (int*)(base + o_dtop);
  unsigned short* whi = (unsigned short*)(base + o_whi);
  unsigned short* wlo = (unsigned short*)(base + o_wlo);

  const int ME = B_ * LE;
  const int MD = B_ * LD;

  auto cast = [&](const float* s, size_t off, int n) {
    k_cast_split<<<n / 1024, 256, 0, stream>>>(s, whi + off, wlo + off, n);
  };
  cast(enc_Wq, wq_e, 131072);  cast(enc_Wk, wk_e, 131072);
  cast(enc_Wv, wv_e, 131072);  cast(enc_Wo, wo_e, 131072);
  cast(enc_W1, w1_e, 524288);  cast(enc_W2, w2_e, 524288);
  cast(sWq, swq_e, 131072);    cast(sWk, swk_e, 131072);
  cast(sWv, swv_e, 131072);    cast(sWo, swo_e, 131072);
  cast(cWq, cwq_e, 131072);    cast(cWk, cwk_e, 131072);
  cast(cWv, cwv_e, 131072);    cast(cWo, cwo_e, 131072);
  cast(dW1, dw1_e, 524288);    cast(dW2, dw2_e, 524288);

  auto gemm = [&](const float* X, size_t woff, const float* bias, float* C,
                  int M, int N, int K, bool relu) {
    int nwg = (M >> 7) * (N >> 7);
    if (relu) k_gemm_split<true ><<<nwg, 256, 0, stream>>>(X, whi + woff, wlo + woff, bias, C, M, N, K);
    else      k_gemm_split<false><<<nwg, 256, 0, stream>>>(X, whi + woff, wlo + woff, bias, C, M, N, K);
  };
  auto ffn = [&](const float* xb, int M, size_t w1, size_t w2) {
    int done = 0;
    while (done < M) {
      int mc = (M - done < 29696) ? (M - done) : 29696;
      gemm(xb + (size_t)done * DM, w1, nullptr, q, mc, DFF, DM, true);
      gemm(q, w2, nullptr, kbuf + (size_t)done * DM, mc, DM, DFF, false);
      done += mc;
    }
  };
  auto attn = [&](const float* src_q, int Lq, const float* src_kv, int S,
                  size_t wq, size_t wk, size_t wv2, size_t wo2,
                  const float* bq, const float* bk, const float* bv, const float* bo, int TK) {
    int Mq = B_ * Lq, Ms = B_ * S;
    gemm(src_q,  wq,  bq, q,    Mq, DM, DM, false);
    gemm(src_kv, wk,  bk, kbuf, Ms, DM, DM, false);
    k_corr_split<<<B_, 256, 0, stream>>>(q, kbuf, wtop, dtop, Lq, S, TK);
    gemm(src_kv, wv2, bv, q, Ms, DM, DM, false);        // V into q (Q dead after corr)
    k_gather3<<<B_ * Lq, 256, 0, stream>>>(q, wtop, dtop, kbuf, Lq, S, TK);
    gemm(kbuf, wo2, bo, q, Mq, DM, DM, false);          // attn out -> q
  };

  // ---- preprocess + embeddings ----
  k_pre<<<B_, 128, 0, stream>>>(x, spad, trend);
  k_conv3<<<B_, 256, 0, stream>>>(x, we_enc, enc, LE);
  k_conv3<<<B_, 256, 0, stream>>>(spad, we_dec, dec, LD);

  // ---- encoder ----
  for (int i = 0; i < 2; ++i) {
    size_t wofs = (size_t)i * 65536, b_ = (size_t)i * DM, f1 = (size_t)i * 262144;
    attn(enc, LE, enc, LE, wq_e + wofs, wk_e + wofs, wv_e + wofs, wo_e + wofs,
         enc_bq + b_, enc_bk + b_, enc_bv + b_, enc_bo + b_, 13);
    k_decomp<0><<<2 * B_, 128, 0, stream>>>(enc, q, enc, nullptr, LE);
    ffn(enc, ME, w1_e + f1, w2_e + f1);
    k_decomp<0><<<2 * B_, 128, 0, stream>>>(enc, kbuf, enc, nullptr, LE);
  }
  k_lnorm<<<B_, 256, 0, stream>>>(enc, enc_g, enc, LE);

  // ---- decoder ----
  for (int i = 0; i < 2; ++i) {
    size_t wofs = (size_t)i * 65536, b_ = (size_t)i * DM, f1 = (size_t)i * 262144;
    const float* Wt_i = dWt + (size_t)i * 5 * DM * 3;
    attn(dec, LD, dec, LD, swq_e + wofs, swk_e + wofs, swv_e + wofs, swo_e + wofs,
         sbq + b_, sbk + b_, sbv + b_, sbo + b_, 14);
    k_decomp<1><<<2 * B_, 128, 0, stream>>>(dec, q, dec, kbuf, LD);
    k_trendconv<<<B_, 256, 0, stream>>>(kbuf, Wt_i, trend, LD);
    attn(dec, LD, enc, LE, cwq_e + wofs, cwk_e + wofs, cwv_e + wofs, cwo_e + wofs,
         cbq + b_, cbk + b_, cbv + b_, cbo + b_, 14);
    k_decomp<1><<<2 * B_, 128, 0, stream>>>(dec, q, dec, kbuf, LD);
    k_trendconv<<<B_, 256, 0, stream>>>(kbuf, Wt_i, trend, LD);
    ffn(dec, MD, dw1_e + f1, dw2_e + f1);
    k_decomp<1><<<2 * B_, 128, 0, stream>>>(dec, kbuf, dec, q, LD);
    k_trendconv<<<B_, 256, 0, stream>>>(q, Wt_i, trend, LD);
  }
  k_lnorm<<<B_, 256, 0, stream>>>(dec, dec_g, dec, LD);

  // ---- output head ----
  k_final<<<B_, 256, 0, stream>>>(dec, trend, projW, projb, bng, bnb, bnrm, bnrv, fcW, fcb, outp);
}

// Round 7
// 6184.857 us; speedup vs baseline: 1.3338x; 1.1267x over previous
//
#include <hip/hip_runtime.h>
#include <hip/hip_bf16.h>
#include <cstdint>
#include <cstddef>

// Autoformer forward, MI355X. Round 7: r6 (passing) with gather rewritten to
// amortize per-block setup: 8 l-values per block, float4 lanes, XCD-affine.
#define B_   1024
#define LE   96
#define LD   116
#define DM   256
#define DFF  1024

typedef __attribute__((ext_vector_type(8))) short bf16x8;
typedef __attribute__((ext_vector_type(4))) float f32x4;

static __device__ __forceinline__ unsigned short f2b(float f) {
  __hip_bfloat16 h = __float2bfloat16(f);
  return *reinterpret_cast<unsigned short*>(&h);
}
static __device__ __forceinline__ float asf(unsigned int u) { return __uint_as_float(u); }

// split 8 f32 -> 8 bf16 hi + 8 bf16 lo (x = hi + lo, residual ~2^-18 relative)
static __device__ __forceinline__ void split8(float4 a, float4 b, uint4& h4, uint4& l4) {
  float f[8] = {a.x, a.y, a.z, a.w, b.x, b.y, b.z, b.w};
  unsigned int hp[4], lp[4];
#pragma unroll
  for (int j = 0; j < 4; ++j) {
    unsigned short h0 = f2b(f[2 * j]);
    unsigned short h1 = f2b(f[2 * j + 1]);
    float r0 = f[2 * j]     - asf((unsigned int)h0 << 16);
    float r1 = f[2 * j + 1] - asf((unsigned int)h1 << 16);
    hp[j] = (unsigned int)h0 | ((unsigned int)h1 << 16);
    lp[j] = (unsigned int)f2b(r0) | ((unsigned int)f2b(r1) << 16);
  }
  h4 = make_uint4(hp[0], hp[1], hp[2], hp[3]);
  l4 = make_uint4(lp[0], lp[1], lp[2], lp[3]);
}

typedef const __attribute__((address_space(1))) void* gas_ptr;
typedef __attribute__((address_space(3))) void* las_ptr;
static __device__ __forceinline__ void gload16(const void* g, void* l) {
  __builtin_amdgcn_global_load_lds((gas_ptr)g, (las_ptr)l, 16, 0, 0);
}

// ---------------- workspace (static; ws_size-independent) ----------------
#define NE_ ((size_t)B_ * LE * DM)
#define ND_ ((size_t)B_ * LD * DM)
#define NS_ ((size_t)B_ * LD * 5)
#define NW_ ((size_t)B_ * 16)
#define WBF_ 3670016

static constexpr size_t o_enc   = 0;
static constexpr size_t o_dec   = o_enc   + NE_ * 4;
static constexpr size_t o_q     = o_dec   + ND_ * 4;
static constexpr size_t o_kbuf  = o_q     + ND_ * 4;
static constexpr size_t o_spad  = o_kbuf  + ND_ * 4;
static constexpr size_t o_trend = o_spad  + NS_ * 4;
static constexpr size_t o_wtop  = o_trend + NS_ * 4;
static constexpr size_t o_dtop  = o_wtop  + NW_ * 4;
static constexpr size_t o_whi   = o_dtop  + NW_ * 4;
static constexpr size_t o_wlo   = o_whi   + (size_t)WBF_ * 2;
static constexpr size_t WS_TOTAL = o_wlo  + (size_t)WBF_ * 2;

__device__ __align__(256) unsigned char g_ws[WS_TOTAL];

static constexpr size_t wq_e = 0, wk_e = 131072, wv_e = 262144, wo_e = 393216;
static constexpr size_t w1_e = 524288, w2_e = 1048576;
static constexpr size_t swq_e = 1572864, swk_e = 1703936, swv_e = 1835008, swo_e = 1966080;
static constexpr size_t cwq_e = 2097152, cwk_e = 2228224, cwv_e = 2359296, cwo_e = 2490368;
static constexpr size_t dw1_e = 2621440, dw2_e = 3145728;

// ---------------- weight split cast ----------------
__global__ __launch_bounds__(256)
void k_cast_split(const float* __restrict__ in, unsigned short* __restrict__ hi,
                  unsigned short* __restrict__ lo, int n) {
  int i = (blockIdx.x * 256 + threadIdx.x) * 4;
  if (i < n) {
    float4 v = *(const float4*)(in + i);
    unsigned int hp[2], lp[2];
    float f[4] = {v.x, v.y, v.z, v.w};
#pragma unroll
    for (int j = 0; j < 2; ++j) {
      unsigned short h0 = f2b(f[2 * j]);
      unsigned short h1 = f2b(f[2 * j + 1]);
      float r0 = f[2 * j]     - asf((unsigned int)h0 << 16);
      float r1 = f[2 * j + 1] - asf((unsigned int)h1 << 16);
      hp[j] = (unsigned int)h0 | ((unsigned int)h1 << 16);
      lp[j] = (unsigned int)f2b(r0) | ((unsigned int)f2b(r1) << 16);
    }
    *(uint2*)(hi + i) = make_uint2(hp[0], hp[1]);
    *(uint2*)(lo + i) = make_uint2(lp[0], lp[1]);
  }
}

// ---------------- preprocess ----------------
__global__ __launch_bounds__(128)
void k_pre(const float* __restrict__ x, float* __restrict__ spad, float* __restrict__ trend) {
  int b = blockIdx.x;
  __shared__ float xs[LE * 5];
  __shared__ float mx[5];
  const float* xb = x + (size_t)b * LE * 5;
  for (int i = threadIdx.x; i < LE * 5; i += 128) xs[i] = xb[i];
  __syncthreads();
  if (threadIdx.x < 5) {
    float s = 0.f;
    for (int t = 0; t < LE; ++t) s += xs[t * 5 + threadIdx.x];
    mx[threadIdx.x] = s * (1.f / 96.f);
  }
  __syncthreads();
  float* spb = spad + (size_t)b * LD * 5;
  float* trb = trend + (size_t)b * LD * 5;
  for (int i = threadIdx.x; i < LE * 5; i += 128) {
    int t = i / 5, c = i % 5;
    float s = 0.f;
    for (int d = -12; d <= 12; ++d) {
      int tt = t + d; tt = tt < 0 ? 0 : (tt > LE - 1 ? LE - 1 : tt);
      s += xs[tt * 5 + c];
    }
    float m = s * (1.f / 25.f);
    trb[t * 5 + c] = m;
    spb[(t + 20) * 5 + c] = xs[i] - m;
  }
  for (int i = threadIdx.x; i < 20 * 5; i += 128) {
    int t = i / 5, c = i % 5;
    spb[t * 5 + c] = 0.f;
    trb[(LE + t) * 5 + c] = mx[c];
  }
}

// ---------------- circular 3-tap conv ----------------
__global__ __launch_bounds__(256)
void k_conv3(const float* __restrict__ xin, const float* __restrict__ W,
             float* __restrict__ out, int L) {
  int b = blockIdx.x, o = threadIdx.x;
  __shared__ float xs[LD * 5];
  const float* xb = xin + (size_t)b * L * 5;
  for (int i = o; i < L * 5; i += 256) xs[i] = xb[i];
  __syncthreads();
  float w[15];
#pragma unroll
  for (int j = 0; j < 15; ++j) w[j] = W[o * 15 + j];
  float* ob = out + (size_t)b * L * DM;
  for (int l = 0; l < L; ++l) {
    int lm = (l == 0) ? L - 1 : l - 1;
    int lp = (l == L - 1) ? 0 : l + 1;
    float acc = 0.f;
#pragma unroll
    for (int c = 0; c < 5; ++c)
      acc += xs[lm * 5 + c] * w[c * 3] + xs[l * 5 + c] * w[c * 3 + 1] + xs[lp * 5 + c] * w[c * 3 + 2];
    ob[(size_t)l * DM + o] = acc;
  }
}

// ---------------- split-bf16 MFMA GEMM (f32-accurate) ----------------
template <bool RELU>
__global__ __launch_bounds__(256)
void k_gemm_split(const float* __restrict__ X,
                  const unsigned short* __restrict__ Whi, const unsigned short* __restrict__ Wlo,
                  const float* __restrict__ bias, float* __restrict__ C,
                  int M, int N, int K) {
  __shared__ __align__(16) unsigned short Xh[4096], Xl[4096], Wh[4096], Wl[4096];
  const int nwg = gridDim.x, bid = blockIdx.x;
  const int wg = (bid & 7) * (nwg >> 3) + (bid >> 3);   // XCD swizzle (nwg%8==0 here)
  const int NT = N >> 7;
  const int mt = wg / NT, nt = wg % NT;                 // nt-fast: X stripe reused on-XCD
  const int m0 = mt << 7, n0 = nt << 7;
  const int tid = threadIdx.x, lane = tid & 63, wv = tid >> 6;
  const int wm = (wv >> 1) << 6, wn = (wv & 1) << 6;

  f32x4 acc[4][4];
#pragma unroll
  for (int i = 0; i < 4; ++i)
#pragma unroll
    for (int j = 0; j < 4; ++j) acc[i][j] = (f32x4){0.f, 0.f, 0.f, 0.f};

  const int r0 = tid >> 2,        ls0 = (tid & 3) ^ ((r0 >> 1) & 3);
  const int r1 = 64 + (tid >> 2), ls1 = (tid & 3) ^ ((r1 >> 1) & 3);
  const unsigned short* wh0 = Whi + (size_t)(n0 + r0) * K + (ls0 << 3);
  const unsigned short* wh1 = Whi + (size_t)(n0 + r1) * K + (ls1 << 3);
  const unsigned short* wl0 = Wlo + (size_t)(n0 + r0) * K + (ls0 << 3);
  const unsigned short* wl1 = Wlo + (size_t)(n0 + r1) * K + (ls1 << 3);
  unsigned short* lwh0 = Wh + ((tid & ~63) << 3);
  unsigned short* lwh1 = Wh + 2048 + ((tid & ~63) << 3);
  unsigned short* lwl0 = Wl + ((tid & ~63) << 3);
  unsigned short* lwl1 = Wl + 2048 + ((tid & ~63) << 3);

  const int xrow0 = tid >> 2, xpart = tid & 3;
  const int xrow1 = 64 + xrow0;
  const float* xp0 = X + (size_t)(m0 + xrow0) * K + (xpart << 3);
  const float* xp1 = X + (size_t)(m0 + xrow1) * K + (xpart << 3);
  const int xph0 = xpart ^ ((xrow0 >> 1) & 3);
  const int xph1 = xpart ^ ((xrow1 >> 1) & 3);
  unsigned short* xh0d = Xh + xrow0 * 32 + (xph0 << 3);
  unsigned short* xl0d = Xl + xrow0 * 32 + (xph0 << 3);
  unsigned short* xh1d = Xh + xrow1 * 32 + (xph1 << 3);
  unsigned short* xl1d = Xl + xrow1 * 32 + (xph1 << 3);

  for (int k0 = 0; k0 < K; k0 += 32) {
    gload16(wh0 + k0, lwh0);
    gload16(wh1 + k0, lwh1);
    gload16(wl0 + k0, lwl0);
    gload16(wl1 + k0, lwl1);
    {
      float4 a0 = *(const float4*)(xp0 + k0);
      float4 b0 = *(const float4*)(xp0 + k0 + 4);
      float4 a1 = *(const float4*)(xp1 + k0);
      float4 b1 = *(const float4*)(xp1 + k0 + 4);
      uint4 h, l;
      split8(a0, b0, h, l);
      *(uint4*)xh0d = h; *(uint4*)xl0d = l;
      split8(a1, b1, h, l);
      *(uint4*)xh1d = h; *(uint4*)xl1d = l;
    }
    __syncthreads();
    bf16x8 ah[4], al[4], bh[4], bl[4];
#pragma unroll
    for (int i = 0; i < 4; ++i) {
      int ra = wm + i * 16 + (lane & 15);
      int sa = (lane >> 4) ^ ((ra >> 1) & 3);
      ah[i] = *(const bf16x8*)(Xh + ra * 32 + (sa << 3));
      al[i] = *(const bf16x8*)(Xl + ra * 32 + (sa << 3));
      int rb = wn + i * 16 + (lane & 15);
      int sb = (lane >> 4) ^ ((rb >> 1) & 3);
      bh[i] = *(const bf16x8*)(Wh + rb * 32 + (sb << 3));
      bl[i] = *(const bf16x8*)(Wl + rb * 32 + (sb << 3));
    }
#pragma unroll
    for (int i = 0; i < 4; ++i)
#pragma unroll
      for (int j = 0; j < 4; ++j) {
        acc[i][j] = __builtin_amdgcn_mfma_f32_16x16x32_bf16(ah[i], bh[j], acc[i][j], 0, 0, 0);
        acc[i][j] = __builtin_amdgcn_mfma_f32_16x16x32_bf16(al[i], bh[j], acc[i][j], 0, 0, 0);
        acc[i][j] = __builtin_amdgcn_mfma_f32_16x16x32_bf16(ah[i], bl[j], acc[i][j], 0, 0, 0);
      }
    __syncthreads();
  }

  const int col_base = n0 + wn + (lane & 15);
  const int row_base = m0 + wm + ((lane >> 4) << 2);
#pragma unroll
  for (int j = 0; j < 4; ++j) {
    int col = col_base + j * 16;
    float bv = bias ? bias[col] : 0.f;
#pragma unroll
    for (int i = 0; i < 4; ++i) {
      int rb2 = row_base + i * 16;
#pragma unroll
      for (int q = 0; q < 4; ++q) {
        float o = acc[i][j][q] + bv;
        if (RELU) o = fmaxf(o, 0.f);
        C[(size_t)(rb2 + q) * N + col] = o;
      }
    }
  }
}

// ---------------- corr (split-bf16 MFMA Gram) + fused top-k/softmax ----------------
__global__ __launch_bounds__(256)
void k_corr_split(const float* __restrict__ Q, const float* __restrict__ Kp,
                  float* __restrict__ wout, int* __restrict__ dout,
                  int L, int S, int TK) {
  __shared__ __align__(16) unsigned char smem[65536];
  unsigned short* qh = (unsigned short*)smem;   // [128][64]
  unsigned short* ql = qh + 8192;
  unsigned short* kh = ql + 8192;
  unsigned short* kl = kh + 8192;
  float* G = (float*)smem;                      // [128][128] overlays after K-loop
  int b = blockIdx.x, tid = threadIdx.x, lane = tid & 63, wv = tid >> 6;
  int wm = (wv >> 1) << 6, wn = (wv & 1) << 6;
  const float* Qb = Q + (size_t)b * L * DM;
  const float* Kb = Kp + (size_t)b * S * DM;
  f32x4 acc[4][4];
#pragma unroll
  for (int i = 0; i < 4; ++i)
#pragma unroll
    for (int j = 0; j < 4; ++j) acc[i][j] = (f32x4){0.f, 0.f, 0.f, 0.f};

  for (int c0 = 0; c0 < DM; c0 += 64) {
#pragma unroll
    for (int u = 0; u < 4; ++u) {
      int seg = (u << 8) + tid;
      int row = seg >> 3, ps = seg & 7;
      int phys = ps ^ (row & 7);
      uint4 h = make_uint4(0u, 0u, 0u, 0u), l = make_uint4(0u, 0u, 0u, 0u);
      if (row < L) {
        float4 a = *(const float4*)(Qb + (size_t)row * DM + c0 + (ps << 3));
        float4 c = *(const float4*)(Qb + (size_t)row * DM + c0 + (ps << 3) + 4);
        split8(a, c, h, l);
      }
      *(uint4*)(qh + row * 64 + (phys << 3)) = h;
      *(uint4*)(ql + row * 64 + (phys << 3)) = l;
      h = make_uint4(0u, 0u, 0u, 0u); l = make_uint4(0u, 0u, 0u, 0u);
      if (row < S) {
        float4 a = *(const float4*)(Kb + (size_t)row * DM + c0 + (ps << 3));
        float4 c = *(const float4*)(Kb + (size_t)row * DM + c0 + (ps << 3) + 4);
        split8(a, c, h, l);
      }
      *(uint4*)(kh + row * 64 + (phys << 3)) = h;
      *(uint4*)(kl + row * 64 + (phys << 3)) = l;
    }
    __syncthreads();
#pragma unroll
    for (int ks = 0; ks < 2; ++ks) {
      bf16x8 aqh[4], aql[4], bkh[4], bkl[4];
#pragma unroll
      for (int i = 0; i < 4; ++i) {
        int ra = wm + i * 16 + (lane & 15);
        int sa = ((ks << 2) + (lane >> 4)) ^ (ra & 7);
        aqh[i] = *(const bf16x8*)(qh + ra * 64 + (sa << 3));
        aql[i] = *(const bf16x8*)(ql + ra * 64 + (sa << 3));
        int rb = wn + i * 16 + (lane & 15);
        int sb = ((ks << 2) + (lane >> 4)) ^ (rb & 7);
        bkh[i] = *(const bf16x8*)(kh + rb * 64 + (sb << 3));
        bkl[i] = *(const bf16x8*)(kl + rb * 64 + (sb << 3));
      }
#pragma unroll
      for (int i = 0; i < 4; ++i)
#pragma unroll
        for (int j = 0; j < 4; ++j) {
          acc[i][j] = __builtin_amdgcn_mfma_f32_16x16x32_bf16(aqh[i], bkh[j], acc[i][j], 0, 0, 0);
          acc[i][j] = __builtin_amdgcn_mfma_f32_16x16x32_bf16(aql[i], bkh[j], acc[i][j], 0, 0, 0);
          acc[i][j] = __builtin_amdgcn_mfma_f32_16x16x32_bf16(aqh[i], bkl[j], acc[i][j], 0, 0, 0);
        }
    }
    __syncthreads();
  }
#pragma unroll
  for (int i = 0; i < 4; ++i)
#pragma unroll
    for (int j = 0; j < 4; ++j)
#pragma unroll
      for (int q = 0; q < 4; ++q)
        G[(wm + i * 16 + ((lane >> 4) << 2) + q) * 128 + wn + j * 16 + (lane & 15)] = acc[i][j][q];
  __syncthreads();
  float s = 0.f;
  if (tid < L) {
    for (int t = 0; t < L; ++t) {
      int r = t - tid; if (r < 0) r += L;
      s += G[t * 128 + r];
    }
    s *= (1.f / 256.f);
  }
  __syncthreads();   // all reads of G done before smem reuse

  float* vals = (float*)smem;            // [128]
  float* rv   = vals + 128;              // [128]
  int*   ri   = (int*)(rv + 128);        // [128]
  float* selv = (float*)(ri + 128);      // [16]
  int*   seli = (int*)(selv + 16);       // [16]
  if (tid < 128) vals[tid] = (tid < L) ? s : -3e38f;
  __syncthreads();
  for (int it = 0; it < TK; ++it) {
    if (tid < 128) { rv[tid] = vals[tid]; ri[tid] = tid; }
    __syncthreads();
    for (int off = 64; off >= 1; off >>= 1) {
      if (tid < off) {
        float v2 = rv[tid + off]; int i2 = ri[tid + off];
        if (v2 > rv[tid] || (v2 == rv[tid] && i2 < ri[tid])) { rv[tid] = v2; ri[tid] = i2; }
      }
      __syncthreads();
    }
    if (tid == 0) { selv[it] = rv[0]; seli[it] = ri[0]; vals[ri[0]] = -3e38f; }
    __syncthreads();
  }
  if (tid == 0) {
    float mxv = selv[0];
    float e[16]; float sum = 0.f;
    for (int j = 0; j < TK; ++j) { e[j] = expf(selv[j] - mxv); sum += e[j]; }
    float inv = 1.f / sum;
    for (int j = 0; j < TK; ++j) {
      wout[(size_t)b * 16 + j] = e[j] * inv;
      dout[(size_t)b * 16 + j] = seli[j];
    }
  }
}

// ---------------- weighted circular gather: 8 l per block, float4, XCD-affine ----------------
// p: xcd = p&7 (= b%8); q8 = p>>3; lg = q8%G8; b = (q8/G8)*8 + xcd.
__global__ __launch_bounds__(256)
void k_gather4(const float* __restrict__ V, const float* __restrict__ wtop,
               const int* __restrict__ dtop, float* __restrict__ out,
               int L, int S, int TK, int G8) {
  int p = blockIdx.x;
  int xcd = p & 7, q8 = p >> 3;
  int lg = q8 % G8;
  int b = ((q8 / G8) << 3) + xcd;
  __shared__ float wsm[16];
  __shared__ int   dsm[16];
  if (threadIdx.x < TK) {
    wsm[threadIdx.x] = wtop[(size_t)b * 16 + threadIdx.x];
    dsm[threadIdx.x] = dtop[(size_t)b * 16 + threadIdx.x];
  }
  __syncthreads();
  int wv = threadIdx.x >> 6, lane = threadIdx.x & 63;
  int c4 = lane << 2;
  const float* Vb = V + (size_t)b * S * DM + c4;
  float* ob = out + (size_t)b * L * DM + c4;
#pragma unroll
  for (int u = 0; u < 2; ++u) {
    int l = (lg << 3) + (wv << 1) + u;
    if (l < L) {
      float ax = 0.f, ay = 0.f, az = 0.f, aw = 0.f;
      for (int j = 0; j < TK; ++j) {
        int r = l + dsm[j]; if (r >= L) r -= L;
        if (r < S) {
          float4 v = *(const float4*)(Vb + (size_t)r * DM);
          float w = wsm[j];
          ax += w * v.x; ay += w * v.y; az += w * v.z; aw += w * v.w;
        }
      }
      float4 o; o.x = ax; o.y = ay; o.z = az; o.w = aw;
      *(float4*)(ob + (size_t)l * DM) = o;
    }
  }
}

// ---------------- series_decomp ----------------
template <int MOUT>
__global__ __launch_bounds__(128)
void k_decomp(const float* __restrict__ X, const float* __restrict__ Y,
              float* __restrict__ out, float* __restrict__ mout, int L) {
  int b = blockIdx.x >> 1, half = blockIdx.x & 1;
  __shared__ float tmp[LD * 128];
  size_t base = (size_t)b * L * DM + half * 128;
  for (int i = threadIdx.x; i < L * 128; i += 128) {
    int t = i >> 7, cc = i & 127;
    size_t gi = base + (size_t)t * DM + cc;
    tmp[i] = X[gi] + Y[gi];
  }
  __syncthreads();
  int tid = threadIdx.x;
  float s = 0.f;
  for (int d = -12; d <= 12; ++d) { int t2 = d < 0 ? 0 : d; s += tmp[t2 * 128 + tid]; }
  for (int t = 0; t < L; ++t) {
    float m = s * (1.f / 25.f);
    size_t gi = base + (size_t)t * DM + tid;
    out[gi] = tmp[t * 128 + tid] - m;
    if (MOUT) mout[gi] = m;
    int ai = t + 13; if (ai > L - 1) ai = L - 1;
    int si = t - 12; if (si < 0) si = 0;
    s += tmp[ai * 128 + tid] - tmp[si * 128 + tid];
  }
}

// ---------------- my_layernorm ----------------
__global__ __launch_bounds__(256)
void k_lnorm(const float* __restrict__ X, const float* __restrict__ g,
             float* __restrict__ out, int L) {
  int b = blockIdx.x;
  __shared__ float mu_s[LD], inv_s[LD];
  size_t base = (size_t)b * L * DM;
  int wv = threadIdx.x >> 6, lane = threadIdx.x & 63;
  for (int t = wv; t < L; t += 4) {
    float s = 0.f, s2 = 0.f;
#pragma unroll
    for (int qd = 0; qd < 4; ++qd) {
      float val = X[base + (size_t)t * DM + lane + 64 * qd];
      s += val; s2 += val * val;
    }
    for (int off = 32; off; off >>= 1) { s += __shfl_xor(s, off); s2 += __shfl_xor(s2, off); }
    if (lane == 0) {
      float mu = s * (1.f / 256.f);
      mu_s[t] = mu;
      inv_s[t] = rsqrtf(s2 * (1.f / 256.f) - mu * mu + 1e-5f);
    }
  }
  __syncthreads();
  int c = threadIdx.x;
  float gc = g[c];
  float sm = 0.f;
  for (int t = 0; t < L; ++t) sm += (X[base + (size_t)t * DM + c] - mu_s[t]) * inv_s[t];
  float mn = sm / (float)L;
  for (int t = 0; t < L; ++t) {
    float xn = (X[base + (size_t)t * DM + c] - mu_s[t]) * inv_s[t];
    out[base + (size_t)t * DM + c] = gc * (xn - mn);
  }
}

// ---------------- trend conv: 1 block/batch, reg weights, wave butterfly ----------------
__global__ __launch_bounds__(256)
void k_trendconv(const float* __restrict__ T, const float* __restrict__ Wt,
                 float* __restrict__ trend, int L) {
  int b = blockIdx.x;
  int tid = threadIdx.x, wv = tid >> 6, lane = tid & 63;
  int c0 = lane << 2;
  float w[5][3][4];
#pragma unroll
  for (int o = 0; o < 5; ++o)
#pragma unroll
    for (int k = 0; k < 4; ++k) {
      w[o][0][k] = Wt[o * 768 + (c0 + k) * 3 + 0];
      w[o][1][k] = Wt[o * 768 + (c0 + k) * 3 + 1];
      w[o][2][k] = Wt[o * 768 + (c0 + k) * 3 + 2];
    }
  size_t base = (size_t)b * L * DM;
  for (int l = wv; l < L; l += 4) {
    int lm = (l == 0) ? L - 1 : l - 1;
    int lp = (l == L - 1) ? 0 : l + 1;
    float4 xm = *(const float4*)(T + base + (size_t)lm * DM + c0);
    float4 x0 = *(const float4*)(T + base + (size_t)l  * DM + c0);
    float4 xp = *(const float4*)(T + base + (size_t)lp * DM + c0);
    float fm[4] = {xm.x, xm.y, xm.z, xm.w};
    float f0[4] = {x0.x, x0.y, x0.z, x0.w};
    float fp[4] = {xp.x, xp.y, xp.z, xp.w};
    float acc[5];
#pragma unroll
    for (int o = 0; o < 5; ++o) {
      float a = 0.f;
#pragma unroll
      for (int k = 0; k < 4; ++k)
        a += fm[k] * w[o][0][k] + f0[k] * w[o][1][k] + fp[k] * w[o][2][k];
      acc[o] = a;
    }
#pragma unroll
    for (int off = 32; off; off >>= 1)
#pragma unroll
      for (int o = 0; o < 5; ++o) acc[o] += __shfl_xor(acc[o], off);
    if (lane == 0) {
#pragma unroll
      for (int o = 0; o < 5; ++o)
        trend[((size_t)b * L + l) * 5 + o] += acc[o];
    }
  }
}

// ---------------- final head ----------------
__global__ __launch_bounds__(256)
void k_final(const float* __restrict__ dec, const float* __restrict__ trend,
             const float* __restrict__ projW, const float* __restrict__ projb,
             const float* __restrict__ bng, const float* __restrict__ bnb,
             const float* __restrict__ bnrm, const float* __restrict__ bnrv,
             const float* __restrict__ fcW, const float* __restrict__ fcb,
             float* __restrict__ outp) {
  int b = blockIdx.x, c = threadIdx.x;
  __shared__ float red[5][256];
  float xv = dec[((size_t)b * LD + (LD - 1)) * DM + c];
#pragma unroll
  for (int o = 0; o < 5; ++o) red[o][c] = xv * projW[o * 256 + c];
  __syncthreads();
  for (int off = 128; off >= 1; off >>= 1) {
    if (c < off) {
#pragma unroll
      for (int o = 0; o < 5; ++o) red[o][c] += red[o][c + off];
    }
    __syncthreads();
  }
  if (c == 0) {
    float acc = fcb[0];
    for (int j = 0; j < 20; ++j) {
      int m5 = j % 5;
      float last = trend[((size_t)b * LD + (LD - 1)) * 5 + m5] + red[m5][0] + projb[m5];
      float h = (last - bnrm[j]) * rsqrtf(bnrv[j] + 1e-5f) * bng[j] + bnb[j];
      acc += h * fcW[j];
    }
    outp[b] = acc;
  }
}

// ================================ host ================================
extern "C" void kernel_launch(void* const* d_in, const int* in_sizes, int n_in,
                              void* d_out, int out_size, void* d_ws, size_t ws_size,
                              hipStream_t stream) {
  const float* x      = (const float*)d_in[0];
  const float* we_enc = (const float*)d_in[1];
  const float* we_dec = (const float*)d_in[2];
  const float* enc_Wq = (const float*)d_in[3];
  const float* enc_bq = (const float*)d_in[4];
  const float* enc_Wk = (const float*)d_in[5];
  const float* enc_bk = (const float*)d_in[6];
  const float* enc_Wv = (const float*)d_in[7];
  const float* enc_bv = (const float*)d_in[8];
  const float* enc_Wo = (const float*)d_in[9];
  const float* enc_bo = (const float*)d_in[10];
  const float* enc_W1 = (const float*)d_in[11];
  const float* enc_W2 = (const float*)d_in[12];
  const float* enc_g  = (const float*)d_in[13];
  const float* sWq = (const float*)d_in[15]; const float* sbq = (const float*)d_in[16];
  const float* sWk = (const float*)d_in[17]; const float* sbk = (const float*)d_in[18];
  const float* sWv = (const float*)d_in[19]; const float* sbv = (const float*)d_in[20];
  const float* sWo = (const float*)d_in[21]; const float* sbo = (const float*)d_in[22];
  const float* cWq = (const float*)d_in[23]; const float* cbq = (const float*)d_in[24];
  const float* cWk = (const float*)d_in[25]; const float* cbk = (const float*)d_in[26];
  const float* cWv = (const float*)d_in[27]; const float* cbv = (const float*)d_in[28];
  const float* cWo = (const float*)d_in[29]; const float* cbo = (const float*)d_in[30];
  const float* dW1 = (const float*)d_in[31]; const float* dW2 = (const float*)d_in[32];
  const float* dWt = (const float*)d_in[33];
  const float* dec_g  = (const float*)d_in[34];
  const float* projW = (const float*)d_in[36]; const float* projb = (const float*)d_in[37];
  const float* bng = (const float*)d_in[38]; const float* bnb = (const float*)d_in[39];
  const float* bnrm = (const float*)d_in[40]; const float* bnrv = (const float*)d_in[41];
  const float* fcW = (const float*)d_in[42]; const float* fcb = (const float*)d_in[43];
  (void)in_sizes; (void)n_in; (void)out_size; (void)d_ws; (void)ws_size;
  float* outp = (float*)d_out;

  void* symaddr = nullptr;
  if (hipGetSymbolAddress(&symaddr, HIP_SYMBOL(g_ws)) != hipSuccess || !symaddr) return;
  unsigned char* base = (unsigned char*)symaddr;
  float* enc   = (float*)(base + o_enc);
  float* dec   = (float*)(base + o_dec);
  float* q     = (float*)(base + o_q);
  float* kbuf  = (float*)(base + o_kbuf);
  float* spad  = (float*)(base + o_spad);
  float* trend = (float*)(base + o_trend);
  float* wtop  = (float*)(base + o_wtop);
  int*   dtop  = (int*)(base + o_dtop);
  unsigned short* whi = (unsigned short*)(base + o_whi);
  unsigned short* wlo = (unsigned short*)(base + o_wlo);

  const int ME = B_ * LE;
  const int MD = B_ * LD;

  auto cast = [&](const float* s, size_t off, int n) {
    k_cast_split<<<n / 1024, 256, 0, stream>>>(s, whi + off, wlo + off, n);
  };
  cast(enc_Wq, wq_e, 131072);  cast(enc_Wk, wk_e, 131072);
  cast(enc_Wv, wv_e, 131072);  cast(enc_Wo, wo_e, 131072);
  cast(enc_W1, w1_e, 524288);  cast(enc_W2, w2_e, 524288);
  cast(sWq, swq_e, 131072);    cast(sWk, swk_e, 131072);
  cast(sWv, swv_e, 131072);    cast(sWo, swo_e, 131072);
  cast(cWq, cwq_e, 131072);    cast(cWk, cwk_e, 131072);
  cast(cWv, cwv_e, 131072);    cast(cWo, cwo_e, 131072);
  cast(dW1, dw1_e, 524288);    cast(dW2, dw2_e, 524288);

  auto gemm = [&](const float* X, size_t woff, const float* bias, float* C,
                  int M, int N, int K, bool relu) {
    int nwg = (M >> 7) * (N >> 7);
    if (relu) k_gemm_split<true ><<<nwg, 256, 0, stream>>>(X, whi + woff, wlo + woff, bias, C, M, N, K);
    else      k_gemm_split<false><<<nwg, 256, 0, stream>>>(X, whi + woff, wlo + woff, bias, C, M, N, K);
  };
  auto ffn = [&](const float* xb, int M, size_t w1, size_t w2) {
    int done = 0;
    while (done < M) {
      int mc = (M - done < 29696) ? (M - done) : 29696;
      gemm(xb + (size_t)done * DM, w1, nullptr, q, mc, DFF, DM, true);
      gemm(q, w2, nullptr, kbuf + (size_t)done * DM, mc, DM, DFF, false);
      done += mc;
    }
  };
  auto attn = [&](const float* src_q, int Lq, const float* src_kv, int S,
                  size_t wq, size_t wk, size_t wv2, size_t wo2,
                  const float* bq, const float* bk, const float* bv, const float* bo, int TK) {
    int Mq = B_ * Lq, Ms = B_ * S;
    int G8 = (Lq + 7) >> 3;
    gemm(src_q,  wq,  bq, q,    Mq, DM, DM, false);
    gemm(src_kv, wk,  bk, kbuf, Ms, DM, DM, false);
    k_corr_split<<<B_, 256, 0, stream>>>(q, kbuf, wtop, dtop, Lq, S, TK);
    gemm(src_kv, wv2, bv, q, Ms, DM, DM, false);        // V into q (Q dead after corr)
    k_gather4<<<B_ * G8, 256, 0, stream>>>(q, wtop, dtop, kbuf, Lq, S, TK, G8);
    gemm(kbuf, wo2, bo, q, Mq, DM, DM, false);          // attn out -> q
  };

  // ---- preprocess + embeddings ----
  k_pre<<<B_, 128, 0, stream>>>(x, spad, trend);
  k_conv3<<<B_, 256, 0, stream>>>(x, we_enc, enc, LE);
  k_conv3<<<B_, 256, 0, stream>>>(spad, we_dec, dec, LD);

  // ---- encoder ----
  for (int i = 0; i < 2; ++i) {
    size_t wofs = (size_t)i * 65536, b_ = (size_t)i * DM, f1 = (size_t)i * 262144;
    attn(enc, LE, enc, LE, wq_e + wofs, wk_e + wofs, wv_e + wofs, wo_e + wofs,
         enc_bq + b_, enc_bk + b_, enc_bv + b_, enc_bo + b_, 13);
    k_decomp<0><<<2 * B_, 128, 0, stream>>>(enc, q, enc, nullptr, LE);
    ffn(enc, ME, w1_e + f1, w2_e + f1);
    k_decomp<0><<<2 * B_, 128, 0, stream>>>(enc, kbuf, enc, nullptr, LE);
  }
  k_lnorm<<<B_, 256, 0, stream>>>(enc, enc_g, enc, LE);

  // ---- decoder ----
  for (int i = 0; i < 2; ++i) {
    size_t wofs = (size_t)i * 65536, b_ = (size_t)i * DM, f1 = (size_t)i * 262144;
    const float* Wt_i = dWt + (size_t)i * 5 * DM * 3;
    attn(dec, LD, dec, LD, swq_e + wofs, swk_e + wofs, swv_e + wofs, swo_e + wofs,
         sbq + b_, sbk + b_, sbv + b_, sbo + b_, 14);
    k_decomp<1><<<2 * B_, 128, 0, stream>>>(dec, q, dec, kbuf, LD);
    k_trendconv<<<B_, 256, 0, stream>>>(kbuf, Wt_i, trend, LD);
    attn(dec, LD, enc, LE, cwq_e + wofs, cwk_e + wofs, cwv_e + wofs, cwo_e + wofs,
         cbq + b_, cbk + b_, cbv + b_, cbo + b_, 14);
    k_decomp<1><<<2 * B_, 128, 0, stream>>>(dec, q, dec, kbuf, LD);
    k_trendconv<<<B_, 256, 0, stream>>>(kbuf, Wt_i, trend, LD);
    ffn(dec, MD, dw1_e + f1, dw2_e + f1);
    k_decomp<1><<<2 * B_, 128, 0, stream>>>(dec, kbuf, dec, q, LD);
    k_trendconv<<<B_, 256, 0, stream>>>(q, Wt_i, trend, LD);
  }
  k_lnorm<<<B_, 256, 0, stream>>>(dec, dec_g, dec, LD);

  // ---- output head ----
  k_final<<<B_, 256, 0, stream>>>(dec, trend, projW, projb, bng, bnb, bnrm, bnrv, fcW, fcb, outp);
}